// Round 5
// baseline (278.005 us; speedup 1.0000x reference)
//
#include <hip/hip_runtime.h>

// Problem: B=2, S=2048, DIM=1024, H=16, DH=64. I/O fp32; internals bf16 MFMA.
#define Bn   2
#define Sn   2048
#define DIMn 1024
#define Hn   16
#define DHn  64

typedef unsigned short u16;
typedef unsigned int   u32;

typedef __attribute__((ext_vector_type(8))) __bf16 bf16x8;
typedef __attribute__((ext_vector_type(8))) float  f32x8v;
typedef __attribute__((ext_vector_type(4))) float  f32x4;

// native HW bf16 convert (RNE, same bits as the old manual round-to-nearest-even)
__device__ __forceinline__ u16 f2bf(float f) {
    union { __bf16 h; u16 u; } v; v.h = (__bf16)f; return v.u;
}
__device__ __forceinline__ bf16x8 ldfrag(const u16* p) {
    union { uint4 u; bf16x8 v; } x;
    x.u = *(const uint4*)p;
    return x.v;
}
__device__ __forceinline__ uint4 pack8(const u16 h[8]) {
    uint4 r;
    r.x = (u32)h[0] | ((u32)h[1] << 16);
    r.y = (u32)h[2] | ((u32)h[3] << 16);
    r.z = (u32)h[4] | ((u32)h[5] << 16);
    r.w = (u32)h[6] | ((u32)h[7] << 16);
    return r;
}
// async 16B global->LDS: lds dest = wave-uniform base + lane*16; global src PER-LANE
__device__ __forceinline__ void gl_lds16(const void* g, void* l) {
    __builtin_amdgcn_global_load_lds(
        (const __attribute__((address_space(1))) void*)g,
        (__attribute__((address_space(3))) void*)l, 16, 0, 0);
}
// raw barrier with compiler-level memory fences on both sides (no vmcnt drain)
__device__ __forceinline__ void barrier_nodrain() {
    asm volatile("" ::: "memory");
    __builtin_amdgcn_s_barrier();
    asm volatile("" ::: "memory");
}

// ---------------------------------------------------------------------------
// Prep: transpose+convert fp32 weights [k][n] -> bf16 CHUNK-TILED Wt.
// Layout: off(z,X,T,o,lane=quad*16+l15,e) =
//   ((((z*8+X)*32+T)*8+o)*64 + quad*16+l15)*8 + e
// holding element (n = X*128+o*16+l15, k = T*32+quad*8+e).
// Every GEMM staging op then reads 1KB CONTIGUOUS (8 cache lines).
// ---------------------------------------------------------------------------
__global__ __launch_bounds__(256) void prep_weights(
    const float* __restrict__ Wq, const float* __restrict__ Wk,
    const float* __restrict__ Wv, const float* __restrict__ Wf,
    u16* __restrict__ Wt)
{
    __shared__ __align__(16) float tile[64][68];
    const float* W = (blockIdx.z == 0) ? Wq : (blockIdx.z == 1) ? Wk
                   : (blockIdx.z == 2) ? Wv : Wf;
    const int t = threadIdx.x;
    const int n0 = blockIdx.x * 64, k0 = blockIdx.y * 64;
    const int rr = t >> 4, cc = (t & 15) * 4;
#pragma unroll
    for (int i = 0; i < 4; i++)
        *(float4*)&tile[rr + 16 * i][cc] =
            *(const float4*)(W + (size_t)(k0 + rr + 16 * i) * DIMn + n0 + cc);
    __syncthreads();
#pragma unroll
    for (int e = 0; e < 2; e++) {
        const int ci = 2 * t + e;
        const int nn = ci >> 3, kc = ci & 7;
        const int n = n0 + nn, k = k0 + kc * 8;
        u16 h[8];
#pragma unroll
        for (int j = 0; j < 8; j++) h[j] = f2bf(tile[kc * 8 + j][nn]);
        const int X = n >> 7, o = (n >> 4) & 7, l15 = n & 15;
        const int T = k >> 5, quad = (k >> 3) & 3;
        const size_t off =
            ((((size_t)(blockIdx.z * 8 + X) * 32 + T) * 8 + o) * 64 + quad * 16 + l15) * 8;
        *(uint4*)(Wt + off) = pack8(h);
    }
}

// ---------------------------------------------------------------------------
// Fused QKV GEMM. A is REG-STAGED: plain global_load_dwordx4 two tiles ahead,
// in-register fp32->bf16 convert, ds_write_b128 into the SAME canonical 1KB
// chunk layout as B. Cuts staged LDS bytes 24->16 KB/iter, makes all fragment
// reads the uniform chunk pattern (conflict-free), LDS 48->32 KB.
// vmcnt group per wave per tile: 4 A-reg loads + 2 B gl_lds = 6 (unchanged).
// Depth-2 pipeline, counted vmcnt(6), raw barriers.
// ---------------------------------------------------------------------------
__global__ __launch_bounds__(256) void gemm_qkv(
    const float* __restrict__ Aq, const float* __restrict__ Ak,
    const float* __restrict__ Av, const u16* __restrict__ Wt,
    const float* __restrict__ bqp, const float* __restrict__ bkp,
    const float* __restrict__ bvp, u16* __restrict__ Qw,
    u16* __restrict__ Kw, u16* __restrict__ VwT)
{
    __shared__ union {
        struct { __align__(16) u16 Abf[2][4096];     // 2 x 8 KB canonical chunks
                 __align__(16) u16 Bbf[2][4096]; } s;  // 2 x 8 KB canonical chunks
        __align__(16) u16 Ep[32][144];               // epilogue staging
    } L;

    // ---- XCD-aware swizzle: f = xcd + 8*(x + 8*(yi + 4*z)) ----
    const int f = blockIdx.x;
    const int xcd = f & 7;
    const int q = f >> 3;
    const int z = q >> 5;
    const int rem = q & 31;
    const int yi = rem >> 3, x = rem & 7;
    const int y = xcd * 4 + yi;
    const int m0 = y * 128, n0 = x * 128;

    const float* A    = (z == 0) ? Aq  : (z == 1) ? Ak  : Av;
    const float* bias = (z == 0) ? bqp : (z == 1) ? bkp : bvp;

    const int t = threadIdx.x;
    const int lane = t & 63, wave = t >> 6;
    const int quad = lane >> 4, l15 = lane & 15;
    const int wm = wave >> 1, wn = wave & 1;

    // A reg-staging: chunk o = wave*2+s holds rows m0+o*16+l15, k quad*8..+8.
    // Lane loads its own 8 fp32 (2x dwordx4) from row m0+o*16+l15.
    const float* baseA[2];
#pragma unroll
    for (int s = 0; s < 2; s++)
        baseA[s] = A + (size_t)(m0 + (wave * 2 + s) * 16 + l15) * DIMn + quad * 8;
    // B staging: chunk-tiled Wt, op o = wave*2+s, 1KB contiguous.
    const u16* baseB[2];
#pragma unroll
    for (int s = 0; s < 2; s++)
        baseB[s] = Wt + ((size_t)((z * 8 + x) * 32) * 8 + (wave * 2 + s)) * 512 + lane * 8;

    auto LOADA = [&](int tt, uint4 (&ar)[4]) {
#pragma unroll
        for (int s = 0; s < 2; s++) {
            const float* p = baseA[s] + tt * 32;
            ar[2 * s]     = *(const uint4*)(p);
            ar[2 * s + 1] = *(const uint4*)(p + 4);
        }
    };
    auto STAGEB = [&](int tt, int buf) {
#pragma unroll
        for (int s = 0; s < 2; s++)
            gl_lds16(baseB[s] + (size_t)tt * 4096, &L.s.Bbf[buf][(wave * 2 + s) * 512]);
    };
    auto CVTWRITE = [&](uint4 (&ar)[4], int buf) {
#pragma unroll
        for (int s = 0; s < 2; s++) {
            union { uint4 u[2]; f32x8v f; } cv;
            cv.u[0] = ar[2 * s]; cv.u[1] = ar[2 * s + 1];
            union { bf16x8 v; uint4 u; } hv;
            hv.v = __builtin_convertvector(cv.f, bf16x8);
            *(uint4*)&L.s.Abf[buf][(wave * 2 + s) * 512 + lane * 8] = hv.u;
        }
    };

    f32x4 acc[4][4];
#pragma unroll
    for (int i = 0; i < 4; i++)
#pragma unroll
        for (int j = 0; j < 4; j++) acc[i][j] = (f32x4){0.f, 0.f, 0.f, 0.f};

    const int NT = DIMn / 32;  // 32
    uint4 ra[4], rb[4];        // static double-buffered A regs (rule #20)
    LOADA(0, ra); STAGEB(0, 0);
    LOADA(1, rb); STAGEB(1, 1);

    auto ITER = [&](int tt, uint4 (&ar)[4], int buf) {
        // retire tile tt's 6 VMEM ops; keep tile tt+1's 6 in flight
        if (tt < NT - 1) asm volatile("s_waitcnt vmcnt(6)" ::: "memory");
        else             asm volatile("s_waitcnt vmcnt(0)" ::: "memory");
        CVTWRITE(ar, buf);  // buf freed for tile tt at iter tt-2's 2nd barrier
        asm volatile("s_waitcnt lgkmcnt(0)" ::: "memory");  // writes visible
        barrier_nodrain();  // all waves' A writes + B DMA data visible

        bf16x8 a[4], b[4];
#pragma unroll
        for (int i = 0; i < 4; i++)
            a[i] = ldfrag(&L.s.Abf[buf][((wm * 4 + i) * 4 + quad) * 128 + l15 * 8]);
#pragma unroll
        for (int j = 0; j < 4; j++)
            b[j] = ldfrag(&L.s.Bbf[buf][((wn * 4 + j) * 4 + quad) * 128 + l15 * 8]);
#pragma unroll
        for (int i = 0; i < 4; i++)
#pragma unroll
            for (int j = 0; j < 4; j++)
                acc[i][j] = __builtin_amdgcn_mfma_f32_16x16x32_bf16(a[i], b[j], acc[i][j], 0, 0, 0);

        asm volatile("s_waitcnt lgkmcnt(0)" ::: "memory");  // reads done
        barrier_nodrain();  // buf free
        if (tt + 2 < NT) { LOADA(tt + 2, ar); STAGEB(tt + 2, buf); }
    };
    for (int tt = 0; tt < NT; tt += 2) { ITER(tt, ra, 0); ITER(tt + 1, rb, 1); }

    float bv[4];
#pragma unroll
    for (int j = 0; j < 4; j++) bv[j] = bias[n0 + wn * 64 + j * 16 + l15];

    const int bb = y >> 4;

    if (z == 0) {
        // ---- Q: [b,h,s,d], phase over i ----
#pragma unroll
        for (int i = 0; i < 4; i++) {
            __syncthreads();
#pragma unroll
            for (int j = 0; j < 4; j++)
#pragma unroll
                for (int r = 0; r < 4; r++)
                    L.Ep[wm * 16 + quad * 4 + r][wn * 64 + j * 16 + l15] =
                        f2bf(acc[i][j][r] + bv[j]);
            __syncthreads();
#pragma unroll
            for (int e = 0; e < 2; e++) {
                const int ci = t + 256 * e;
                const int row = ci >> 4, c = ci & 15;
                const uint4 v = *(const uint4*)&L.Ep[row][c * 8];
                const int m = m0 + (row >> 4) * 64 + i * 16 + (row & 15);
                const int ss = m & 2047;
                const int n = n0 + c * 8;
                const int hh = n >> 6, dd = n & 63;
                *(uint4*)(Qw + ((size_t)(bb * Hn + hh) * Sn + ss) * DHn + dd) = v;
            }
        }
    } else if (z == 1) {
        // ---- K: attn-chunk-tiled; wave-contiguous 1KB stores ----
#pragma unroll
        for (int i = 0; i < 4; i++) {
            __syncthreads();
#pragma unroll
            for (int j = 0; j < 4; j++)
#pragma unroll
                for (int r = 0; r < 4; r++)
                    L.Ep[wm * 16 + quad * 4 + r][wn * 64 + j * 16 + l15] =
                        f2bf(acc[i][j][r] + bv[j]);
            __syncthreads();
#pragma unroll
            for (int e2 = 0; e2 < 2; e2++) {
                const int tid = t + 256 * e2;
                const int l15o = tid & 15;
                const int qo   = (tid >> 4) & 3;
                const int k1   = (tid >> 6) & 1;
                const int c3   = (tid >> 7) & 1;
                const int w    = (tid >> 8) & 1;
                const int c    = c3 * 8 + k1 * 4 + qo;
                const uint4 v = *(const uint4*)&L.Ep[w * 16 + l15o][c * 8];
                const int ss = (m0 & 2047) + w * 64 + i * 16 + l15o;
                const int hh = (n0 + c * 8) >> 6;
                const int jt = ss >> 6;
                const int o  = i * 2 + k1;
                const size_t off =
                    ((((size_t)(bb * Hn + hh) * 32 + jt) * 8 + o) * 64 + qo * 16 + l15o) * 8;
                *(uint4*)(Kw + off) = v;
            }
        }
    } else {
        // ---- V: attn-chunk-tiled (transposed fill), phase over j ----
#pragma unroll
        for (int j = 0; j < 4; j++) {
            __syncthreads();
#pragma unroll
            for (int i = 0; i < 4; i++) {
                u16 h4[4];
#pragma unroll
                for (int r = 0; r < 4; r++) h4[r] = f2bf(acc[i][j][r] + bv[j]);
                uint2 pk;
                pk.x = (u32)h4[0] | ((u32)h4[1] << 16);
                pk.y = (u32)h4[2] | ((u32)h4[3] << 16);
                *(uint2*)&L.Ep[wn * 16 + l15][wm * 64 + i * 16 + quad * 4] = pk;
            }
            __syncthreads();
#pragma unroll
            for (int e2 = 0; e2 < 2; e2++) {
                const int tid = t + 256 * e2;
                const int l15o = tid & 15;
                const int qo   = (tid >> 4) & 3;
                const int k1   = (tid >> 6) & 1;
                const int c3   = (tid >> 7) & 1;
                const int w    = (tid >> 8) & 1;
                const int c    = c3 * 8 + k1 * 4 + qo;
                const uint4 v = *(const uint4*)&L.Ep[w * 16 + l15o][c * 8];
                const int n  = n0 + w * 64 + j * 16 + l15o;
                const int hh = n >> 6;
                const int jt = ((m0 & 2047) >> 6) + c3;
                const int o  = j * 2 + k1;
                const size_t off =
                    ((((size_t)(bb * Hn + hh) * 32 + jt) * 8 + o) * 64 + qo * 16 + l15o) * 8;
                *(uint4*)(VwT + off) = v;
            }
        }
    }
}

// ---------------------------------------------------------------------------
// Final GEMM, depth-3 pipeline. B from chunk-tiled Wt (contiguous 1KB ops).
// A (attn output in [b,h,s,d]) staging unchanged.
// ---------------------------------------------------------------------------
__global__ __launch_bounds__(256) void gemm_final(
    const u16* __restrict__ A, const u16* __restrict__ Bt,
    const float* __restrict__ bias, float* __restrict__ out)
{
    __shared__ __align__(16) u16 Abf[3][32 * 128];  // 3 x 8 KB chunked
    __shared__ __align__(16) u16 Bbf[3][32 * 128];  // 3 x 8 KB chunked

    const int f = blockIdx.x;
    const int xcd = f & 7, q = f >> 3;
    const int y = xcd * 4 + (q >> 3), x = q & 7;
    const int m0 = y * 128, n0 = x * 128;

    const int t = threadIdx.x;
    const int lane = t & 63, wave = t >> 6;
    const int quad = lane >> 4, l15 = lane & 15;
    const int wm = wave >> 1, wn = wave & 1;

    int arow[2], aq[2];
#pragma unroll
    for (int s = 0; s < 2; s++) {
        const int c = wave * 8 + s * 4 + quad;
        arow[s] = (c >> 2) * 16 + l15;  // local m row
        aq[s] = c & 3;
    }
    const u16* baseB[2];
#pragma unroll
    for (int s = 0; s < 2; s++)
        baseB[s] = Bt + ((size_t)(x * 32) * 8 + (wave * 2 + s)) * 512 + lane * 8;

    auto STAGE = [&](int tt, int buf) {
        const int hh = tt >> 1, d64 = (tt & 1) * 32;
#pragma unroll
        for (int s = 0; s < 2; s++) {
            const int m = m0 + arow[s], bb = m >> 11, ss = m & 2047;
            const u16* gp = A + ((size_t)(bb * Hn + hh) * Sn + ss) * DHn + d64 + aq[s] * 8;
            gl_lds16(gp, &Abf[buf][(wave * 8 + s * 4) * 128]);
        }
#pragma unroll
        for (int s = 0; s < 2; s++)
            gl_lds16(baseB[s] + (size_t)tt * 4096, &Bbf[buf][(wave * 8 + s * 4) * 128]);
    };

    f32x4 acc[4][4];
#pragma unroll
    for (int i = 0; i < 4; i++)
#pragma unroll
        for (int j = 0; j < 4; j++) acc[i][j] = (f32x4){0.f, 0.f, 0.f, 0.f};

    const int NT = DIMn / 32;  // 32
    STAGE(0, 0);
    STAGE(1, 1);
    STAGE(2, 2);

    int buf = 0;
    for (int tt = 0; tt < NT; ++tt) {
        if (tt < NT - 2)       asm volatile("s_waitcnt vmcnt(8)" ::: "memory");
        else if (tt == NT - 2) asm volatile("s_waitcnt vmcnt(4)" ::: "memory");
        else                   asm volatile("s_waitcnt vmcnt(0)" ::: "memory");
        barrier_nodrain();

        bf16x8 a[4], b[4];
#pragma unroll
        for (int i = 0; i < 4; i++)
            a[i] = ldfrag(&Abf[buf][((wm * 4 + i) * 4 + quad) * 128 + l15 * 8]);
#pragma unroll
        for (int j = 0; j < 4; j++)
            b[j] = ldfrag(&Bbf[buf][((wn * 4 + j) * 4 + quad) * 128 + l15 * 8]);
#pragma unroll
        for (int i = 0; i < 4; i++)
#pragma unroll
            for (int j = 0; j < 4; j++)
                acc[i][j] = __builtin_amdgcn_mfma_f32_16x16x32_bf16(a[i], b[j], acc[i][j], 0, 0, 0);

        asm volatile("s_waitcnt lgkmcnt(0)" ::: "memory");
        barrier_nodrain();
        if (tt + 3 < NT) STAGE(tt + 3, buf);
        buf = (buf == 2) ? 0 : buf + 1;
    }

    float bv[4];
#pragma unroll
    for (int j = 0; j < 4; j++) bv[j] = bias[n0 + wn * 64 + j * 16 + l15];

#pragma unroll
    for (int i = 0; i < 4; i++)
#pragma unroll
        for (int j = 0; j < 4; j++) {
            const int n = n0 + wn * 64 + j * 16 + l15;
#pragma unroll
            for (int r = 0; r < 4; r++) {
                const int m = m0 + wm * 64 + i * 16 + quad * 4 + r;
                out[(size_t)m * DIMn + n] = acc[i][j][r] + bv[j];
            }
        }
}

// ---------------------------------------------------------------------------
// MFMA flash attention. K/V chunk-tiled (1KB contiguous staging ops), depth-2
// pipeline, vmcnt(4). Mask staged in the prologue with plain int4 loads and
// bit-packed per lane. T5: s_setprio(1) around MFMA clusters. Epilogue
// restages O through Ps for uint4 row-contiguous stores.
// ---------------------------------------------------------------------------
__global__ __launch_bounds__(256) void attn_mfma(
    const u16* __restrict__ Qw, const u16* __restrict__ Kw,
    const u16* __restrict__ VwT, const int* __restrict__ mask,
    const int* __restrict__ tstat, u16* __restrict__ Aw)
{
    __shared__ __align__(16) u16 Kbf[2][32 * 128];  // 2 x 8 KB chunked
    __shared__ __align__(16) u16 Vbf[2][32 * 128];  // 2 x 8 KB chunked
    __shared__ __align__(16) u16 Ps[64 * 64];       // 8 KB, XOR-swizzled in loop

    const int f = blockIdx.x;
    const int xcd = f & 7, q = f >> 3;
    const int p = xcd * 4 + (q >> 5);
    const int qt = q & 31;
    const int b = p >> 4, h = p & 15;
    const int q0 = qt * 64;

    const int t = threadIdx.x;
    const int lane = t & 63, wave = t >> 6;
    const int quad = lane >> 4, l15 = lane & 15;
    const bool use_mask = (tstat[0] != 0);
    const size_t slab = (size_t)(b * Hn + h) * Sn * DHn;

    // Tiled K/V staging bases: head slab = 32 tiles x 8 chunks x 512 u16
    const size_t hbase = (size_t)(b * Hn + h) * 32 * 8 * 512;
    const u16* baseK[2];
    const u16* baseV[2];
#pragma unroll
    for (int s = 0; s < 2; s++) {
        const int o = wave * 2 + s;
        baseK[s] = Kw  + hbase + (size_t)o * 512 + lane * 8;
        baseV[s] = VwT + hbase + (size_t)o * 512 + lane * 8;
    }

    // ---- prologue: stage full 8 KB mask into Kbf[0] with plain loads ----
    {
        const int4* msrc4 = (const int4*)(mask + (size_t)b * Sn);  // 512 int4
        int4* mdst4 = (int4*)&Kbf[0][0];
        mdst4[t]       = msrc4[t];
        mdst4[t + 256] = msrc4[t + 256];
    }
    bf16x8 aq[2];
#pragma unroll
    for (int ks = 0; ks < 2; ks++) {
        union { uint4 u; bf16x8 v; } xx;
        xx.u = *(const uint4*)(Qw + slab + (size_t)(q0 + wave * 16 + l15) * DHn + ks * 32 + quad * 8);
        aq[ks] = xx.v;
    }
    __syncthreads();  // Q in regs, full mask visible in LDS

    // ---- pack this lane's mask bits: bit k = (mask[k*16 + l15] != 0) ----
    u32 mw0 = 0, mw1 = 0, mw2 = 0, mw3 = 0;
    {
        const int* ml = (const int*)&Kbf[0][0];
#pragma unroll
        for (int k = 0; k < 128; k++) {
            const u32 bit = (ml[k * 16 + l15] != 0) ? 1u : 0u;
            if (k < 32)      mw0 |= bit << k;
            else if (k < 64) mw1 |= bit << (k - 32);
            else if (k < 96) mw2 |= bit << (k - 64);
            else             mw3 |= bit << (k - 96);
        }
    }
    __syncthreads();  // pack reads retired before Kbf[0] reuse

    auto STAGE = [&](int tt, int buf) {
#pragma unroll
        for (int s = 0; s < 2; s++) {
            gl_lds16(baseK[s] + (size_t)tt * 4096, &Kbf[buf][(wave * 8 + s * 4) * 128]);
            gl_lds16(baseV[s] + (size_t)tt * 4096, &Vbf[buf][(wave * 8 + s * 4) * 128]);
        }
    };

    float lsum[4] = {0.f, 0.f, 0.f, 0.f};
    f32x4 O[4];
#pragma unroll
    for (int dt = 0; dt < 4; dt++) O[dt] = (f32x4){0.f, 0.f, 0.f, 0.f};

    const int NT = Sn / 64;  // 32
    STAGE(0, 0);
    STAGE(1, 1);

#pragma unroll 2
    for (int tt = 0; tt < NT; ++tt) {
        const int buf = tt & 1;
        if (tt < NT - 1) asm volatile("s_waitcnt vmcnt(4)" ::: "memory");
        else             asm volatile("s_waitcnt vmcnt(0)" ::: "memory");
        barrier_nodrain();

        // ---- S = Q K^T ----
        f32x4 s[4];
#pragma unroll
        for (int ct = 0; ct < 4; ct++) s[ct] = (f32x4){0.f, 0.f, 0.f, 0.f};
        __builtin_amdgcn_s_setprio(1);
#pragma unroll
        for (int ct = 0; ct < 4; ct++)
#pragma unroll
            for (int ks = 0; ks < 2; ks++) {
                const bf16x8 bk = ldfrag(&Kbf[buf][(ct * 8 + ks * 4 + quad) * 128 + l15 * 8]);
                s[ct] = __builtin_amdgcn_mfma_f32_16x16x32_bf16(aq[ks], bk, s[ct], 0, 0, 0);
            }
        __builtin_amdgcn_s_setprio(0);

        // ---- mask bits for this tile: k = tt*4 + ct ----
        const int wsel = tt >> 3;
        const u32 cw = (wsel == 0) ? mw0 : (wsel == 1) ? mw1 : (wsel == 2) ? mw2 : mw3;
        const int sh = (tt & 7) * 4;
        u32 mc[4];
#pragma unroll
        for (int ct = 0; ct < 4; ct++)
            mc[ct] = use_mask ? ((cw >> (sh + ct)) & 1u) : 1u;

        // ---- P = exp(mask ? s/64 : -1e9); accumulate l; stash P ----
#pragma unroll
        for (int ct = 0; ct < 4; ct++)
#pragma unroll
            for (int r = 0; r < 4; r++) {
                const float sv = mc[ct] ? s[ct][r] * (1.0f / 64.0f) : -1e9f;
                const float pp = __expf(sv);
                lsum[r] += pp;
                const int prow = wave * 16 + quad * 4 + r;
                Ps[prow * 64 + ((ct * 16 + l15) ^ ((prow & 7) << 3))] = f2bf(pp);
            }
        asm volatile("s_waitcnt lgkmcnt(0)" ::: "memory");  // wave-private band

        // ---- O += P V ----
        bf16x8 pa[2];
        const int rrow = wave * 16 + l15;
#pragma unroll
        for (int kc = 0; kc < 2; kc++)
            pa[kc] = ldfrag(&Ps[rrow * 64 + ((kc * 32 + quad * 8) ^ ((l15 & 7) << 3))]);
        __builtin_amdgcn_s_setprio(1);
#pragma unroll
        for (int dt = 0; dt < 4; dt++)
#pragma unroll
            for (int kc = 0; kc < 2; kc++) {
                const bf16x8 bvv = ldfrag(&Vbf[buf][(dt * 8 + kc * 4 + quad) * 128 + l15 * 8]);
                O[dt] = __builtin_amdgcn_mfma_f32_16x16x32_bf16(pa[kc], bvv, O[dt], 0, 0, 0);
            }
        __builtin_amdgcn_s_setprio(0);

        asm volatile("s_waitcnt lgkmcnt(0)" ::: "memory");
        barrier_nodrain();
        if (tt + 2 < NT) STAGE(tt + 2, buf);
    }

    // ---- reduce l across the 16 column-lanes ----
#pragma unroll
    for (int r = 0; r < 4; r++) {
#pragma unroll
        for (int off = 1; off < 16; off <<= 1) lsum[r] += __shfl_xor(lsum[r], off);
    }
    float linv[4];
#pragma unroll
    for (int r = 0; r < 4; r++) linv[r] = 1.0f / fmaxf(lsum[r], 1e-30f);

    // ---- epilogue: restage O in Ps (plain), then uint4 row stores ----
    __syncthreads();
#pragma unroll
    for (int r = 0; r < 4; r++)
#pragma unroll
        for (int dt = 0; dt < 4; dt++)
            Ps[(wave * 16 + quad * 4 + r) * 64 + dt * 16 + l15] = f2bf(O[dt][r] * linv[r]);
    __syncthreads();
#pragma unroll
    for (int e2 = 0; e2 < 2; e2++) {
        const int tid = t + 256 * e2;
        const int lr = tid >> 3, c16 = tid & 7;
        const uint4 v = *(const uint4*)&Ps[lr * 64 + c16 * 8];
        *(uint4*)(Aw + slab + (size_t)(q0 + lr) * DHn + c16 * 8) = v;
    }
}

// ---------------------------------------------------------------------------
extern "C" void kernel_launch(void* const* d_in, const int* in_sizes, int n_in,
                              void* d_out, int out_size, void* d_ws, size_t ws_size,
                              hipStream_t stream) {
    const float* query = (const float*)d_in[0];
    const float* key   = (const float*)d_in[1];
    const float* value = (const float*)d_in[2];
    const int*   pmask = (const int*)d_in[3];
    const int*   tstat = (const int*)d_in[4];
    const float* Wq  = (const float*)d_in[5];
    const float* bq  = (const float*)d_in[6];
    const float* Wk  = (const float*)d_in[7];
    const float* bk  = (const float*)d_in[8];
    const float* Wv  = (const float*)d_in[9];
    const float* bv  = (const float*)d_in[10];
    const float* Wf  = (const float*)d_in[11];
    const float* bfb = (const float*)d_in[12];
    float* outp = (float*)d_out;

    // ws (32 MB): Qw(8, attn-out alias) | Kw tiled(8) | VwT tiled(8) | Wt tiled 4x2MB(8)
    const size_t NT = (size_t)Bn * Sn * DIMn;
    u16* Qw  = (u16*)d_ws;
    u16* Kw  = Qw + NT;
    u16* VwT = Kw + NT;
    u16* Wt  = VwT + NT;
    const size_t WSZ = (size_t)DIMn * DIMn;

    prep_weights<<<dim3(16, 16, 4), 256, 0, stream>>>(Wq, Wk, Wv, Wf, Wt);

    gemm_qkv<<<768, 256, 0, stream>>>(query, key, value, Wt, bq, bk, bv, Qw, Kw, VwT);

    attn_mfma<<<1024, 256, 0, stream>>>(Qw, Kw, VwT, pmask, tstat, Qw);

    gemm_final<<<256, 256, 0, stream>>>(Qw, Wt + 3 * WSZ, bfb, outp);
}

// Round 6
// 271.226 us; speedup vs baseline: 1.0250x; 1.0250x over previous
//
#include <hip/hip_runtime.h>

// Problem: B=2, S=2048, DIM=1024, H=16, DH=64. I/O fp32; internals bf16 MFMA.
#define Bn   2
#define Sn   2048
#define DIMn 1024
#define Hn   16
#define DHn  64

typedef unsigned short u16;
typedef unsigned int   u32;

typedef __attribute__((ext_vector_type(8))) __bf16 bf16x8;
typedef __attribute__((ext_vector_type(8))) float  f32x8v;
typedef __attribute__((ext_vector_type(4))) float  f32x4;

// native HW bf16 convert (RNE)
__device__ __forceinline__ u16 f2bf(float f) {
    union { __bf16 h; u16 u; } v; v.h = (__bf16)f; return v.u;
}
__device__ __forceinline__ bf16x8 ldfrag(const u16* p) {
    union { uint4 u; bf16x8 v; } x;
    x.u = *(const uint4*)p;
    return x.v;
}
__device__ __forceinline__ uint4 pack8(const u16 h[8]) {
    uint4 r;
    r.x = (u32)h[0] | ((u32)h[1] << 16);
    r.y = (u32)h[2] | ((u32)h[3] << 16);
    r.z = (u32)h[4] | ((u32)h[5] << 16);
    r.w = (u32)h[6] | ((u32)h[7] << 16);
    return r;
}
// async 16B global->LDS: lds dest = wave-uniform base + lane*16; global src PER-LANE
__device__ __forceinline__ void gl_lds16(const void* g, void* l) {
    __builtin_amdgcn_global_load_lds(
        (const __attribute__((address_space(1))) void*)g,
        (__attribute__((address_space(3))) void*)l, 16, 0, 0);
}
// raw barrier with compiler-level memory fences on both sides (no vmcnt drain)
__device__ __forceinline__ void barrier_nodrain() {
    asm volatile("" ::: "memory");
    __builtin_amdgcn_s_barrier();
    asm volatile("" ::: "memory");
}

// ---------------------------------------------------------------------------
// Prep: transpose+convert fp32 weights [k][n] -> bf16 CHUNK-TILED Wt.
// Layout: off(z,X,T,o,lane=quad*16+l15,e) =
//   ((((z*8+X)*32+T)*8+o)*64 + quad*16+l15)*8 + e
// holding element (n = X*128+o*16+l15, k = T*32+quad*8+e).
// ---------------------------------------------------------------------------
__global__ __launch_bounds__(256) void prep_weights(
    const float* __restrict__ Wq, const float* __restrict__ Wk,
    const float* __restrict__ Wv, const float* __restrict__ Wf,
    u16* __restrict__ Wt)
{
    __shared__ __align__(16) float tile[64][68];
    const float* W = (blockIdx.z == 0) ? Wq : (blockIdx.z == 1) ? Wk
                   : (blockIdx.z == 2) ? Wv : Wf;
    const int t = threadIdx.x;
    const int n0 = blockIdx.x * 64, k0 = blockIdx.y * 64;
    const int rr = t >> 4, cc = (t & 15) * 4;
#pragma unroll
    for (int i = 0; i < 4; i++)
        *(float4*)&tile[rr + 16 * i][cc] =
            *(const float4*)(W + (size_t)(k0 + rr + 16 * i) * DIMn + n0 + cc);
    __syncthreads();
#pragma unroll
    for (int e = 0; e < 2; e++) {
        const int ci = 2 * t + e;
        const int nn = ci >> 3, kc = ci & 7;
        const int n = n0 + nn, k = k0 + kc * 8;
        u16 h[8];
#pragma unroll
        for (int j = 0; j < 8; j++) h[j] = f2bf(tile[kc * 8 + j][nn]);
        const int X = n >> 7, o = (n >> 4) & 7, l15 = n & 15;
        const int T = k >> 5, quad = (k >> 3) & 3;
        const size_t off =
            ((((size_t)(blockIdx.z * 8 + X) * 32 + T) * 8 + o) * 64 + quad * 16 + l15) * 8;
        *(uint4*)(Wt + off) = pack8(h);
    }
}

// ---------------------------------------------------------------------------
// Fused QKV GEMM. A reg-staged (global->reg->cvt->ds_write canonical chunks),
// B via gl_lds from chunk-tiled Wt. Depth-2 pipeline, counted vmcnt(6).
// ---------------------------------------------------------------------------
__global__ __launch_bounds__(256) void gemm_qkv(
    const float* __restrict__ Aq, const float* __restrict__ Ak,
    const float* __restrict__ Av, const u16* __restrict__ Wt,
    const float* __restrict__ bqp, const float* __restrict__ bkp,
    const float* __restrict__ bvp, u16* __restrict__ Qw,
    u16* __restrict__ Kw, u16* __restrict__ VwT)
{
    __shared__ union {
        struct { __align__(16) u16 Abf[2][4096];     // 2 x 8 KB canonical chunks
                 __align__(16) u16 Bbf[2][4096]; } s;  // 2 x 8 KB canonical chunks
        __align__(16) u16 Ep[32][144];               // epilogue staging
    } L;

    // ---- XCD-aware swizzle: f = xcd + 8*(x + 8*(yi + 4*z)) ----
    const int f = blockIdx.x;
    const int xcd = f & 7;
    const int q = f >> 3;
    const int z = q >> 5;
    const int rem = q & 31;
    const int yi = rem >> 3, x = rem & 7;
    const int y = xcd * 4 + yi;
    const int m0 = y * 128, n0 = x * 128;

    const float* A    = (z == 0) ? Aq  : (z == 1) ? Ak  : Av;
    const float* bias = (z == 0) ? bqp : (z == 1) ? bkp : bvp;

    const int t = threadIdx.x;
    const int lane = t & 63, wave = t >> 6;
    const int quad = lane >> 4, l15 = lane & 15;
    const int wm = wave >> 1, wn = wave & 1;

    const float* baseA[2];
#pragma unroll
    for (int s = 0; s < 2; s++)
        baseA[s] = A + (size_t)(m0 + (wave * 2 + s) * 16 + l15) * DIMn + quad * 8;
    const u16* baseB[2];
#pragma unroll
    for (int s = 0; s < 2; s++)
        baseB[s] = Wt + ((size_t)((z * 8 + x) * 32) * 8 + (wave * 2 + s)) * 512 + lane * 8;

    auto LOADA = [&](int tt, uint4 (&ar)[4]) {
#pragma unroll
        for (int s = 0; s < 2; s++) {
            const float* p = baseA[s] + tt * 32;
            ar[2 * s]     = *(const uint4*)(p);
            ar[2 * s + 1] = *(const uint4*)(p + 4);
        }
    };
    auto STAGEB = [&](int tt, int buf) {
#pragma unroll
        for (int s = 0; s < 2; s++)
            gl_lds16(baseB[s] + (size_t)tt * 4096, &L.s.Bbf[buf][(wave * 2 + s) * 512]);
    };
    auto CVTWRITE = [&](uint4 (&ar)[4], int buf) {
#pragma unroll
        for (int s = 0; s < 2; s++) {
            union { uint4 u[2]; f32x8v f; } cv;
            cv.u[0] = ar[2 * s]; cv.u[1] = ar[2 * s + 1];
            union { bf16x8 v; uint4 u; } hv;
            hv.v = __builtin_convertvector(cv.f, bf16x8);
            *(uint4*)&L.s.Abf[buf][(wave * 2 + s) * 512 + lane * 8] = hv.u;
        }
    };

    f32x4 acc[4][4];
#pragma unroll
    for (int i = 0; i < 4; i++)
#pragma unroll
        for (int j = 0; j < 4; j++) acc[i][j] = (f32x4){0.f, 0.f, 0.f, 0.f};

    const int NT = DIMn / 32;  // 32
    uint4 ra[4], rb[4];        // static double-buffered A regs (rule #20)
    LOADA(0, ra); STAGEB(0, 0);
    LOADA(1, rb); STAGEB(1, 1);

    auto ITER = [&](int tt, uint4 (&ar)[4], int buf) {
        if (tt < NT - 1) asm volatile("s_waitcnt vmcnt(6)" ::: "memory");
        else             asm volatile("s_waitcnt vmcnt(0)" ::: "memory");
        CVTWRITE(ar, buf);
        asm volatile("s_waitcnt lgkmcnt(0)" ::: "memory");
        barrier_nodrain();

        bf16x8 a[4], b[4];
#pragma unroll
        for (int i = 0; i < 4; i++)
            a[i] = ldfrag(&L.s.Abf[buf][((wm * 4 + i) * 4 + quad) * 128 + l15 * 8]);
#pragma unroll
        for (int j = 0; j < 4; j++)
            b[j] = ldfrag(&L.s.Bbf[buf][((wn * 4 + j) * 4 + quad) * 128 + l15 * 8]);
#pragma unroll
        for (int i = 0; i < 4; i++)
#pragma unroll
            for (int j = 0; j < 4; j++)
                acc[i][j] = __builtin_amdgcn_mfma_f32_16x16x32_bf16(a[i], b[j], acc[i][j], 0, 0, 0);

        asm volatile("s_waitcnt lgkmcnt(0)" ::: "memory");
        barrier_nodrain();
        if (tt + 2 < NT) { LOADA(tt + 2, ar); STAGEB(tt + 2, buf); }
    };
    for (int tt = 0; tt < NT; tt += 2) { ITER(tt, ra, 0); ITER(tt + 1, rb, 1); }

    float bv[4];
#pragma unroll
    for (int j = 0; j < 4; j++) bv[j] = bias[n0 + wn * 64 + j * 16 + l15];

    const int bb = y >> 4;

    if (z == 0) {
        // ---- Q: [b,h,s,d], phase over i ----
#pragma unroll
        for (int i = 0; i < 4; i++) {
            __syncthreads();
#pragma unroll
            for (int j = 0; j < 4; j++)
#pragma unroll
                for (int r = 0; r < 4; r++)
                    L.Ep[wm * 16 + quad * 4 + r][wn * 64 + j * 16 + l15] =
                        f2bf(acc[i][j][r] + bv[j]);
            __syncthreads();
#pragma unroll
            for (int e = 0; e < 2; e++) {
                const int ci = t + 256 * e;
                const int row = ci >> 4, c = ci & 15;
                const uint4 v = *(const uint4*)&L.Ep[row][c * 8];
                const int m = m0 + (row >> 4) * 64 + i * 16 + (row & 15);
                const int ss = m & 2047;
                const int n = n0 + c * 8;
                const int hh = n >> 6, dd = n & 63;
                *(uint4*)(Qw + ((size_t)(bb * Hn + hh) * Sn + ss) * DHn + dd) = v;
            }
        }
    } else if (z == 1) {
        // ---- K: attn-chunk-tiled; wave-contiguous 1KB stores ----
#pragma unroll
        for (int i = 0; i < 4; i++) {
            __syncthreads();
#pragma unroll
            for (int j = 0; j < 4; j++)
#pragma unroll
                for (int r = 0; r < 4; r++)
                    L.Ep[wm * 16 + quad * 4 + r][wn * 64 + j * 16 + l15] =
                        f2bf(acc[i][j][r] + bv[j]);
            __syncthreads();
#pragma unroll
            for (int e2 = 0; e2 < 2; e2++) {
                const int tid = t + 256 * e2;
                const int l15o = tid & 15;
                const int qo   = (tid >> 4) & 3;
                const int k1   = (tid >> 6) & 1;
                const int c3   = (tid >> 7) & 1;
                const int w    = (tid >> 8) & 1;
                const int c    = c3 * 8 + k1 * 4 + qo;
                const uint4 v = *(const uint4*)&L.Ep[w * 16 + l15o][c * 8];
                const int ss = (m0 & 2047) + w * 64 + i * 16 + l15o;
                const int hh = (n0 + c * 8) >> 6;
                const int jt = ss >> 6;
                const int o  = i * 2 + k1;
                const size_t off =
                    ((((size_t)(bb * Hn + hh) * 32 + jt) * 8 + o) * 64 + qo * 16 + l15o) * 8;
                *(uint4*)(Kw + off) = v;
            }
        }
    } else {
        // ---- V: attn-chunk-tiled (transposed fill), phase over j ----
#pragma unroll
        for (int j = 0; j < 4; j++) {
            __syncthreads();
#pragma unroll
            for (int i = 0; i < 4; i++) {
                u16 h4[4];
#pragma unroll
                for (int r = 0; r < 4; r++) h4[r] = f2bf(acc[i][j][r] + bv[j]);
                uint2 pk;
                pk.x = (u32)h4[0] | ((u32)h4[1] << 16);
                pk.y = (u32)h4[2] | ((u32)h4[3] << 16);
                *(uint2*)&L.Ep[wn * 16 + l15][wm * 64 + i * 16 + quad * 4] = pk;
            }
            __syncthreads();
#pragma unroll
            for (int e2 = 0; e2 < 2; e2++) {
                const int tid = t + 256 * e2;
                const int l15o = tid & 15;
                const int qo   = (tid >> 4) & 3;
                const int k1   = (tid >> 6) & 1;
                const int c3   = (tid >> 7) & 1;
                const int w    = (tid >> 8) & 1;
                const int c    = c3 * 8 + k1 * 4 + qo;
                const uint4 v = *(const uint4*)&L.Ep[w * 16 + l15o][c * 8];
                const int n  = n0 + w * 64 + j * 16 + l15o;
                const int hh = n >> 6;
                const int jt = ((m0 & 2047) >> 6) + c3;
                const int o  = j * 2 + k1;
                const size_t off =
                    ((((size_t)(bb * Hn + hh) * 32 + jt) * 8 + o) * 64 + qo * 16 + l15o) * 8;
                *(uint4*)(VwT + off) = v;
            }
        }
    }
}

// ---------------------------------------------------------------------------
// Final GEMM: tile 128(m) x 64(n), BK=64, grid 512 (2 blocks/CU). A from the
// CHUNK-TILED attn output (1KB contiguous DMAs), B from chunk-tiled Wt.
// Per wave per tile: 4 A + 2 B gl_lds = 6; depth-2, counted vmcnt(6).
// LDS: 2 x (16KB A + 8KB B) = 48 KB.
// ---------------------------------------------------------------------------
__global__ __launch_bounds__(256) void gemm_final(
    const u16* __restrict__ A, const u16* __restrict__ Bt,
    const float* __restrict__ bias, float* __restrict__ out)
{
    __shared__ __align__(16) u16 Abf[2][16 * 512];  // 2 x 16 KB
    __shared__ __align__(16) u16 Bbf[2][8 * 512];   // 2 x 8 KB

    const int f = blockIdx.x;                // 512 blocks
    const int xcd = f & 7, q = f >> 3;       // q in [0,64)
    const int y = xcd * 4 + (q >> 4);        // [0,32) m-tile
    const int x = q & 15;                    // [0,16) n-tile
    const int m0 = y * 128, n0 = x * 64;
    const int bb = y >> 4;
    const int jtb = (y & 15) * 2;            // jt base within head

    const int t = threadIdx.x;
    const int lane = t & 63, wave = t >> 6;
    const int quad = lane >> 4, l15 = lane & 15;
    const int wm = wave >> 1, wn = wave & 1;

    // A: chunks c = wave*4+s; c = (jt2*4+sub16)*2 + dsub
    const u16* baseA[4];
#pragma unroll
    for (int s = 0; s < 4; s++) {
        const int c = wave * 4 + s;
        const int g = c >> 1, dsub = c & 1;
        const int jt2 = g >> 2, sub16 = g & 3;
        baseA[s] = A + (((size_t)(bb * Hn) * 32 + jtb + jt2) * 8 + (sub16 * 2 + dsub)) * 512
                     + lane * 8;
    }
    // B: chunks cb = wave*2+s; cb = os*2 + ksub; Wt z=3 slab addressing (64-wide n)
    const u16* baseB[2];
#pragma unroll
    for (int s = 0; s < 2; s++) {
        const int cb = wave * 2 + s;
        const int os = cb >> 1, ksub = cb & 1;
        baseB[s] = Bt + (((size_t)(x >> 1) * 32 + ksub) * 8 + ((x & 1) * 4 + os)) * 512
                      + lane * 8;
    }

    auto STAGE = [&](int tt, int buf) {
#pragma unroll
        for (int s = 0; s < 4; s++)
            gl_lds16(baseA[s] + (size_t)tt * 131072, &Abf[buf][(wave * 4 + s) * 512]);
#pragma unroll
        for (int s = 0; s < 2; s++)
            gl_lds16(baseB[s] + (size_t)tt * 8192, &Bbf[buf][(wave * 2 + s) * 512]);
    };

    f32x4 acc[4][2];
#pragma unroll
    for (int i = 0; i < 4; i++)
#pragma unroll
        for (int j = 0; j < 2; j++) acc[i][j] = (f32x4){0.f, 0.f, 0.f, 0.f};

    const int NT = 16;  // one k-block (64) per head
    STAGE(0, 0);
    STAGE(1, 1);

    for (int tt = 0; tt < NT; ++tt) {
        const int buf = tt & 1;
        if (tt < NT - 1) asm volatile("s_waitcnt vmcnt(6)" ::: "memory");
        else             asm volatile("s_waitcnt vmcnt(0)" ::: "memory");
        barrier_nodrain();

        bf16x8 a[4][2], b[2][2];
#pragma unroll
        for (int i = 0; i < 4; i++)
#pragma unroll
            for (int ks = 0; ks < 2; ks++) {
                const int c = (wm * 4 + i) * 2 + ks;
                a[i][ks] = ldfrag(&Abf[buf][c * 512 + (quad * 16 + l15) * 8]);
            }
#pragma unroll
        for (int j = 0; j < 2; j++)
#pragma unroll
            for (int ks = 0; ks < 2; ks++) {
                const int cb = (wn * 2 + j) * 2 + ks;
                b[j][ks] = ldfrag(&Bbf[buf][cb * 512 + (quad * 16 + l15) * 8]);
            }
#pragma unroll
        for (int i = 0; i < 4; i++)
#pragma unroll
            for (int j = 0; j < 2; j++)
#pragma unroll
                for (int ks = 0; ks < 2; ks++)
                    acc[i][j] = __builtin_amdgcn_mfma_f32_16x16x32_bf16(
                        a[i][ks], b[j][ks], acc[i][j], 0, 0, 0);

        asm volatile("s_waitcnt lgkmcnt(0)" ::: "memory");
        barrier_nodrain();
        if (tt + 2 < NT) STAGE(tt + 2, buf);
    }

    float bv[2];
#pragma unroll
    for (int j = 0; j < 2; j++) bv[j] = bias[n0 + wn * 32 + j * 16 + l15];

#pragma unroll
    for (int i = 0; i < 4; i++)
#pragma unroll
        for (int j = 0; j < 2; j++) {
            const int n = n0 + wn * 32 + j * 16 + l15;
#pragma unroll
            for (int r = 0; r < 4; r++) {
                const int m = m0 + wm * 64 + i * 16 + quad * 4 + r;
                out[(size_t)m * DIMn + n] = acc[i][j][r] + bv[j];
            }
        }
}

// ---------------------------------------------------------------------------
// MFMA flash attention. K/V chunk-tiled staging, depth-2 vmcnt(4) pipeline.
// No setprio (m190: hurts lockstep blocks). Softmax mask via per-ct fma bias.
// Epilogue writes the output in CANONICAL CHUNK layout (consumed by
// gemm_final) over the same 8KB slab this block's Q occupied (alias-safe).
// ---------------------------------------------------------------------------
__global__ __launch_bounds__(256) void attn_mfma(
    const u16* __restrict__ Qw, const u16* __restrict__ Kw,
    const u16* __restrict__ VwT, const int* __restrict__ mask,
    const int* __restrict__ tstat, u16* __restrict__ Aw)
{
    __shared__ __align__(16) u16 Kbf[2][32 * 128];  // 2 x 8 KB chunked
    __shared__ __align__(16) u16 Vbf[2][32 * 128];  // 2 x 8 KB chunked
    __shared__ __align__(16) u16 Ps[64 * 64];       // 8 KB, XOR-swizzled in loop

    const int f = blockIdx.x;
    const int xcd = f & 7, q = f >> 3;
    const int p = xcd * 4 + (q >> 5);
    const int qt = q & 31;
    const int b = p >> 4, h = p & 15;
    const int q0 = qt * 64;

    const int t = threadIdx.x;
    const int lane = t & 63, wave = t >> 6;
    const int quad = lane >> 4, l15 = lane & 15;
    const bool use_mask = (tstat[0] != 0);
    const size_t slab = (size_t)(b * Hn + h) * Sn * DHn;

    // Tiled K/V staging bases: head slab = 32 tiles x 8 chunks x 512 u16
    const size_t hbase = (size_t)(b * Hn + h) * 32 * 8 * 512;
    const u16* baseK[2];
    const u16* baseV[2];
#pragma unroll
    for (int s = 0; s < 2; s++) {
        const int o = wave * 2 + s;
        baseK[s] = Kw  + hbase + (size_t)o * 512 + lane * 8;
        baseV[s] = VwT + hbase + (size_t)o * 512 + lane * 8;
    }

    // ---- prologue: stage full 8 KB mask into Kbf[0] with plain loads ----
    {
        const int4* msrc4 = (const int4*)(mask + (size_t)b * Sn);  // 512 int4
        int4* mdst4 = (int4*)&Kbf[0][0];
        mdst4[t]       = msrc4[t];
        mdst4[t + 256] = msrc4[t + 256];
    }
    bf16x8 aq[2];
#pragma unroll
    for (int ks = 0; ks < 2; ks++) {
        union { uint4 u; bf16x8 v; } xx;
        xx.u = *(const uint4*)(Qw + slab + (size_t)(q0 + wave * 16 + l15) * DHn + ks * 32 + quad * 8);
        aq[ks] = xx.v;
    }
    __syncthreads();  // Q in regs, full mask visible in LDS

    // ---- pack this lane's mask bits: bit k = (mask[k*16 + l15] != 0) ----
    u32 mw0 = 0, mw1 = 0, mw2 = 0, mw3 = 0;
    {
        const int* ml = (const int*)&Kbf[0][0];
#pragma unroll
        for (int k = 0; k < 128; k++) {
            const u32 bit = (ml[k * 16 + l15] != 0) ? 1u : 0u;
            if (k < 32)      mw0 |= bit << k;
            else if (k < 64) mw1 |= bit << (k - 32);
            else if (k < 96) mw2 |= bit << (k - 64);
            else             mw3 |= bit << (k - 96);
        }
    }
    __syncthreads();  // pack reads retired before Kbf[0] reuse

    auto STAGE = [&](int tt, int buf) {
#pragma unroll
        for (int s = 0; s < 2; s++) {
            gl_lds16(baseK[s] + (size_t)tt * 4096, &Kbf[buf][(wave * 8 + s * 4) * 128]);
            gl_lds16(baseV[s] + (size_t)tt * 4096, &Vbf[buf][(wave * 8 + s * 4) * 128]);
        }
    };

    float lsum[4] = {0.f, 0.f, 0.f, 0.f};
    f32x4 O[4];
#pragma unroll
    for (int dt = 0; dt < 4; dt++) O[dt] = (f32x4){0.f, 0.f, 0.f, 0.f};

    const int NT = Sn / 64;  // 32
    STAGE(0, 0);
    STAGE(1, 1);

#pragma unroll 2
    for (int tt = 0; tt < NT; ++tt) {
        const int buf = tt & 1;
        if (tt < NT - 1) asm volatile("s_waitcnt vmcnt(4)" ::: "memory");
        else             asm volatile("s_waitcnt vmcnt(0)" ::: "memory");
        barrier_nodrain();

        // ---- S = Q K^T ----
        f32x4 s[4];
#pragma unroll
        for (int ct = 0; ct < 4; ct++) s[ct] = (f32x4){0.f, 0.f, 0.f, 0.f};
#pragma unroll
        for (int ct = 0; ct < 4; ct++)
#pragma unroll
            for (int ks = 0; ks < 2; ks++) {
                const bf16x8 bk = ldfrag(&Kbf[buf][(ct * 8 + ks * 4 + quad) * 128 + l15 * 8]);
                s[ct] = __builtin_amdgcn_mfma_f32_16x16x32_bf16(aq[ks], bk, s[ct], 0, 0, 0);
            }

        // ---- mask bias for this tile: k = tt*4 + ct ----
        const int wsel = tt >> 3;
        const u32 cw = (wsel == 0) ? mw0 : (wsel == 1) ? mw1 : (wsel == 2) ? mw2 : mw3;
        const int sh = (tt & 7) * 4;
        float badd[4];
#pragma unroll
        for (int ct = 0; ct < 4; ct++)
            badd[ct] = (!use_mask || ((cw >> (sh + ct)) & 1u)) ? 0.0f : -1e9f;

        // ---- P = exp(s/64 + badd); accumulate l; stash P ----
#pragma unroll
        for (int ct = 0; ct < 4; ct++)
#pragma unroll
            for (int r = 0; r < 4; r++) {
                const float pp = __expf(fmaf(s[ct][r], 1.0f / 64.0f, badd[ct]));
                lsum[r] += pp;
                const int prow = wave * 16 + quad * 4 + r;
                Ps[prow * 64 + ((ct * 16 + l15) ^ ((prow & 7) << 3))] = f2bf(pp);
            }
        asm volatile("s_waitcnt lgkmcnt(0)" ::: "memory");  // wave-private band

        // ---- O += P V ----
        bf16x8 pa[2];
        const int rrow = wave * 16 + l15;
#pragma unroll
        for (int kc = 0; kc < 2; kc++)
            pa[kc] = ldfrag(&Ps[rrow * 64 + ((kc * 32 + quad * 8) ^ ((l15 & 7) << 3))]);
#pragma unroll
        for (int dt = 0; dt < 4; dt++)
#pragma unroll
            for (int kc = 0; kc < 2; kc++) {
                const bf16x8 bvv = ldfrag(&Vbf[buf][(dt * 8 + kc * 4 + quad) * 128 + l15 * 8]);
                O[dt] = __builtin_amdgcn_mfma_f32_16x16x32_bf16(pa[kc], bvv, O[dt], 0, 0, 0);
            }

        asm volatile("s_waitcnt lgkmcnt(0)" ::: "memory");
        barrier_nodrain();
        if (tt + 2 < NT) STAGE(tt + 2, buf);
    }

    // ---- reduce l across the 16 column-lanes ----
#pragma unroll
    for (int r = 0; r < 4; r++) {
#pragma unroll
        for (int off = 1; off < 16; off <<= 1) lsum[r] += __shfl_xor(lsum[r], off);
    }
    float linv[4];
#pragma unroll
    for (int r = 0; r < 4; r++) linv[r] = 1.0f / fmaxf(lsum[r], 1e-30f);

    // ---- epilogue: restage O in Ps (plain), then store CHUNK-TILED ----
    __syncthreads();
#pragma unroll
    for (int r = 0; r < 4; r++)
#pragma unroll
        for (int dt = 0; dt < 4; dt++)
            Ps[(wave * 16 + quad * 4 + r) * 64 + dt * 16 + l15] = f2bf(O[dt][r] * linv[r]);
    __syncthreads();
    const size_t cbase = ((size_t)(b * Hn + h) * 32 + qt) * 4096;  // == Q slab (8KB)
#pragma unroll
    for (int e2 = 0; e2 < 2; e2++) {
        const int tid = t + 256 * e2;
        const int row = tid >> 3, cg = tid & 7;
        const int sub16 = row >> 4, dsub = cg >> 2, quadk = cg & 3;
        const uint4 v = *(const uint4*)&Ps[row * 64 + cg * 8];
        *(uint4*)(Aw + cbase + (size_t)(sub16 * 2 + dsub) * 512
                  + (quadk * 16 + (row & 15)) * 8) = v;
    }
}

// ---------------------------------------------------------------------------
extern "C" void kernel_launch(void* const* d_in, const int* in_sizes, int n_in,
                              void* d_out, int out_size, void* d_ws, size_t ws_size,
                              hipStream_t stream) {
    const float* query = (const float*)d_in[0];
    const float* key   = (const float*)d_in[1];
    const float* value = (const float*)d_in[2];
    const int*   pmask = (const int*)d_in[3];
    const int*   tstat = (const int*)d_in[4];
    const float* Wq  = (const float*)d_in[5];
    const float* bq  = (const float*)d_in[6];
    const float* Wk  = (const float*)d_in[7];
    const float* bk  = (const float*)d_in[8];
    const float* Wv  = (const float*)d_in[9];
    const float* bv  = (const float*)d_in[10];
    const float* Wf  = (const float*)d_in[11];
    const float* bfb = (const float*)d_in[12];
    float* outp = (float*)d_out;

    // ws (32 MB): Qw(8, attn-out alias) | Kw tiled(8) | VwT tiled(8) | Wt tiled 4x2MB(8)
    const size_t NT = (size_t)Bn * Sn * DIMn;
    u16* Qw  = (u16*)d_ws;
    u16* Kw  = Qw + NT;
    u16* VwT = Kw + NT;
    u16* Wt  = VwT + NT;
    const size_t WSZ = (size_t)DIMn * DIMn;

    prep_weights<<<dim3(16, 16, 4), 256, 0, stream>>>(Wq, Wk, Wv, Wf, Wt);

    gemm_qkv<<<768, 256, 0, stream>>>(query, key, value, Wt, bq, bk, bv, Qw, Kw, VwT);

    attn_mfma<<<1024, 256, 0, stream>>>(Qw, Kw, VwT, pmask, tstat, Qw);

    gemm_final<<<512, 256, 0, stream>>>(Qw, Wt + 3 * WSZ, bfb, outp);
}

// Round 7
// 268.302 us; speedup vs baseline: 1.0362x; 1.0109x over previous
//
#include <hip/hip_runtime.h>

// Problem: B=2, S=2048, DIM=1024, H=16, DH=64. I/O fp32; internals bf16 MFMA.
#define Bn   2
#define Sn   2048
#define DIMn 1024
#define Hn   16
#define DHn  64

typedef unsigned short u16;
typedef unsigned int   u32;

typedef __attribute__((ext_vector_type(8))) __bf16 bf16x8;
typedef __attribute__((ext_vector_type(8))) float  f32x8v;
typedef __attribute__((ext_vector_type(4))) float  f32x4;

// manual RNE f32->bf16 (3-4 VALU ops; native __bf16 cast lowers to the
// IEEE __truncsfbf2 pattern with cmp/cndmask — measurably slower in the
// attn softmax chain). Bit-identical results on non-NaN inputs.
__device__ __forceinline__ u16 f2bf(float f) {
    union { float f; u32 u; } v; v.f = f;
    u32 r = v.u + 0x7fffu + ((v.u >> 16) & 1u);  // RNE
    return (u16)(r >> 16);
}
__device__ __forceinline__ bf16x8 ldfrag(const u16* p) {
    union { uint4 u; bf16x8 v; } x;
    x.u = *(const uint4*)p;
    return x.v;
}
__device__ __forceinline__ uint4 pack8(const u16 h[8]) {
    uint4 r;
    r.x = (u32)h[0] | ((u32)h[1] << 16);
    r.y = (u32)h[2] | ((u32)h[3] << 16);
    r.z = (u32)h[4] | ((u32)h[5] << 16);
    r.w = (u32)h[6] | ((u32)h[7] << 16);
    return r;
}
// async 16B global->LDS: lds dest = wave-uniform base + lane*16; global src PER-LANE
__device__ __forceinline__ void gl_lds16(const void* g, void* l) {
    __builtin_amdgcn_global_load_lds(
        (const __attribute__((address_space(1))) void*)g,
        (__attribute__((address_space(3))) void*)l, 16, 0, 0);
}
// raw barrier with compiler-level memory fences on both sides (no vmcnt drain)
__device__ __forceinline__ void barrier_nodrain() {
    asm volatile("" ::: "memory");
    __builtin_amdgcn_s_barrier();
    asm volatile("" ::: "memory");
}

// ---------------------------------------------------------------------------
// Prep: transpose+convert fp32 weights [k][n] -> bf16 CHUNK-TILED Wt.
// Layout: off(z,X,T,o,lane=quad*16+l15,e) =
//   ((((z*8+X)*32+T)*8+o)*64 + quad*16+l15)*8 + e
// holding element (n = X*128+o*16+l15, k = T*32+quad*8+e).
// ---------------------------------------------------------------------------
__global__ __launch_bounds__(256) void prep_weights(
    const float* __restrict__ Wq, const float* __restrict__ Wk,
    const float* __restrict__ Wv, const float* __restrict__ Wf,
    u16* __restrict__ Wt)
{
    __shared__ __align__(16) float tile[64][68];
    const float* W = (blockIdx.z == 0) ? Wq : (blockIdx.z == 1) ? Wk
                   : (blockIdx.z == 2) ? Wv : Wf;
    const int t = threadIdx.x;
    const int n0 = blockIdx.x * 64, k0 = blockIdx.y * 64;
    const int rr = t >> 4, cc = (t & 15) * 4;
#pragma unroll
    for (int i = 0; i < 4; i++)
        *(float4*)&tile[rr + 16 * i][cc] =
            *(const float4*)(W + (size_t)(k0 + rr + 16 * i) * DIMn + n0 + cc);
    __syncthreads();
#pragma unroll
    for (int e = 0; e < 2; e++) {
        const int ci = 2 * t + e;
        const int nn = ci >> 3, kc = ci & 7;
        const int n = n0 + nn, k = k0 + kc * 8;
        u16 h[8];
#pragma unroll
        for (int j = 0; j < 8; j++) h[j] = f2bf(tile[kc * 8 + j][nn]);
        const int X = n >> 7, o = (n >> 4) & 7, l15 = n & 15;
        const int T = k >> 5, quad = (k >> 3) & 3;
        const size_t off =
            ((((size_t)(blockIdx.z * 8 + X) * 32 + T) * 8 + o) * 64 + quad * 16 + l15) * 8;
        *(uint4*)(Wt + off) = pack8(h);
    }
}

// ---------------------------------------------------------------------------
// Fused QKV GEMM. A reg-staged (global->reg->cvt->ds_write canonical chunks),
// B via gl_lds from chunk-tiled Wt. Depth-2 pipeline, counted vmcnt(6).
// ---------------------------------------------------------------------------
__global__ __launch_bounds__(256) void gemm_qkv(
    const float* __restrict__ Aq, const float* __restrict__ Ak,
    const float* __restrict__ Av, const u16* __restrict__ Wt,
    const float* __restrict__ bqp, const float* __restrict__ bkp,
    const float* __restrict__ bvp, u16* __restrict__ Qw,
    u16* __restrict__ Kw, u16* __restrict__ VwT)
{
    __shared__ union {
        struct { __align__(16) u16 Abf[2][4096];     // 2 x 8 KB canonical chunks
                 __align__(16) u16 Bbf[2][4096]; } s;  // 2 x 8 KB canonical chunks
        __align__(16) u16 Ep[32][144];               // epilogue staging
    } L;

    // ---- XCD-aware swizzle: f = xcd + 8*(x + 8*(yi + 4*z)) ----
    const int f = blockIdx.x;
    const int xcd = f & 7;
    const int q = f >> 3;
    const int z = q >> 5;
    const int rem = q & 31;
    const int yi = rem >> 3, x = rem & 7;
    const int y = xcd * 4 + yi;
    const int m0 = y * 128, n0 = x * 128;

    const float* A    = (z == 0) ? Aq  : (z == 1) ? Ak  : Av;
    const float* bias = (z == 0) ? bqp : (z == 1) ? bkp : bvp;

    const int t = threadIdx.x;
    const int lane = t & 63, wave = t >> 6;
    const int quad = lane >> 4, l15 = lane & 15;
    const int wm = wave >> 1, wn = wave & 1;

    const float* baseA[2];
#pragma unroll
    for (int s = 0; s < 2; s++)
        baseA[s] = A + (size_t)(m0 + (wave * 2 + s) * 16 + l15) * DIMn + quad * 8;
    const u16* baseB[2];
#pragma unroll
    for (int s = 0; s < 2; s++)
        baseB[s] = Wt + ((size_t)((z * 8 + x) * 32) * 8 + (wave * 2 + s)) * 512 + lane * 8;

    auto LOADA = [&](int tt, uint4 (&ar)[4]) {
#pragma unroll
        for (int s = 0; s < 2; s++) {
            const float* p = baseA[s] + tt * 32;
            ar[2 * s]     = *(const uint4*)(p);
            ar[2 * s + 1] = *(const uint4*)(p + 4);
        }
    };
    auto STAGEB = [&](int tt, int buf) {
#pragma unroll
        for (int s = 0; s < 2; s++)
            gl_lds16(baseB[s] + (size_t)tt * 4096, &L.s.Bbf[buf][(wave * 2 + s) * 512]);
    };
    auto CVTWRITE = [&](uint4 (&ar)[4], int buf) {
#pragma unroll
        for (int s = 0; s < 2; s++) {
            union { uint4 u[2]; f32x8v f; } cv;
            cv.u[0] = ar[2 * s]; cv.u[1] = ar[2 * s + 1];
            union { bf16x8 v; uint4 u; } hv;
            hv.v = __builtin_convertvector(cv.f, bf16x8);
            *(uint4*)&L.s.Abf[buf][(wave * 2 + s) * 512 + lane * 8] = hv.u;
        }
    };

    f32x4 acc[4][4];
#pragma unroll
    for (int i = 0; i < 4; i++)
#pragma unroll
        for (int j = 0; j < 4; j++) acc[i][j] = (f32x4){0.f, 0.f, 0.f, 0.f};

    const int NT = DIMn / 32;  // 32
    uint4 ra[4], rb[4];        // static double-buffered A regs (rule #20)
    LOADA(0, ra); STAGEB(0, 0);
    LOADA(1, rb); STAGEB(1, 1);

    auto ITER = [&](int tt, uint4 (&ar)[4], int buf) {
        if (tt < NT - 1) asm volatile("s_waitcnt vmcnt(6)" ::: "memory");
        else             asm volatile("s_waitcnt vmcnt(0)" ::: "memory");
        CVTWRITE(ar, buf);
        asm volatile("s_waitcnt lgkmcnt(0)" ::: "memory");
        barrier_nodrain();

        bf16x8 a[4], b[4];
#pragma unroll
        for (int i = 0; i < 4; i++)
            a[i] = ldfrag(&L.s.Abf[buf][((wm * 4 + i) * 4 + quad) * 128 + l15 * 8]);
#pragma unroll
        for (int j = 0; j < 4; j++)
            b[j] = ldfrag(&L.s.Bbf[buf][((wn * 4 + j) * 4 + quad) * 128 + l15 * 8]);
#pragma unroll
        for (int i = 0; i < 4; i++)
#pragma unroll
            for (int j = 0; j < 4; j++)
                acc[i][j] = __builtin_amdgcn_mfma_f32_16x16x32_bf16(a[i], b[j], acc[i][j], 0, 0, 0);

        asm volatile("s_waitcnt lgkmcnt(0)" ::: "memory");
        barrier_nodrain();
        if (tt + 2 < NT) { LOADA(tt + 2, ar); STAGEB(tt + 2, buf); }
    };
    for (int tt = 0; tt < NT; tt += 2) { ITER(tt, ra, 0); ITER(tt + 1, rb, 1); }

    float bv[4];
#pragma unroll
    for (int j = 0; j < 4; j++) bv[j] = bias[n0 + wn * 64 + j * 16 + l15];

    const int bb = y >> 4;

    if (z == 0) {
        // ---- Q: [b,h,s,d], phase over i ----
#pragma unroll
        for (int i = 0; i < 4; i++) {
            __syncthreads();
#pragma unroll
            for (int j = 0; j < 4; j++)
#pragma unroll
                for (int r = 0; r < 4; r++)
                    L.Ep[wm * 16 + quad * 4 + r][wn * 64 + j * 16 + l15] =
                        f2bf(acc[i][j][r] + bv[j]);
            __syncthreads();
#pragma unroll
            for (int e = 0; e < 2; e++) {
                const int ci = t + 256 * e;
                const int row = ci >> 4, c = ci & 15;
                const uint4 v = *(const uint4*)&L.Ep[row][c * 8];
                const int m = m0 + (row >> 4) * 64 + i * 16 + (row & 15);
                const int ss = m & 2047;
                const int n = n0 + c * 8;
                const int hh = n >> 6, dd = n & 63;
                *(uint4*)(Qw + ((size_t)(bb * Hn + hh) * Sn + ss) * DHn + dd) = v;
            }
        }
    } else if (z == 1) {
        // ---- K: attn-chunk-tiled; wave-contiguous 1KB stores ----
#pragma unroll
        for (int i = 0; i < 4; i++) {
            __syncthreads();
#pragma unroll
            for (int j = 0; j < 4; j++)
#pragma unroll
                for (int r = 0; r < 4; r++)
                    L.Ep[wm * 16 + quad * 4 + r][wn * 64 + j * 16 + l15] =
                        f2bf(acc[i][j][r] + bv[j]);
            __syncthreads();
#pragma unroll
            for (int e2 = 0; e2 < 2; e2++) {
                const int tid = t + 256 * e2;
                const int l15o = tid & 15;
                const int qo   = (tid >> 4) & 3;
                const int k1   = (tid >> 6) & 1;
                const int c3   = (tid >> 7) & 1;
                const int w    = (tid >> 8) & 1;
                const int c    = c3 * 8 + k1 * 4 + qo;
                const uint4 v = *(const uint4*)&L.Ep[w * 16 + l15o][c * 8];
                const int ss = (m0 & 2047) + w * 64 + i * 16 + l15o;
                const int hh = (n0 + c * 8) >> 6;
                const int jt = ss >> 6;
                const int o  = i * 2 + k1;
                const size_t off =
                    ((((size_t)(bb * Hn + hh) * 32 + jt) * 8 + o) * 64 + qo * 16 + l15o) * 8;
                *(uint4*)(Kw + off) = v;
            }
        }
    } else {
        // ---- V: attn-chunk-tiled (transposed fill), phase over j ----
#pragma unroll
        for (int j = 0; j < 4; j++) {
            __syncthreads();
#pragma unroll
            for (int i = 0; i < 4; i++) {
                u16 h4[4];
#pragma unroll
                for (int r = 0; r < 4; r++) h4[r] = f2bf(acc[i][j][r] + bv[j]);
                uint2 pk;
                pk.x = (u32)h4[0] | ((u32)h4[1] << 16);
                pk.y = (u32)h4[2] | ((u32)h4[3] << 16);
                *(uint2*)&L.Ep[wn * 16 + l15][wm * 64 + i * 16 + quad * 4] = pk;
            }
            __syncthreads();
#pragma unroll
            for (int e2 = 0; e2 < 2; e2++) {
                const int tid = t + 256 * e2;
                const int l15o = tid & 15;
                const int qo   = (tid >> 4) & 3;
                const int k1   = (tid >> 6) & 1;
                const int c3   = (tid >> 7) & 1;
                const int w    = (tid >> 8) & 1;
                const int c    = c3 * 8 + k1 * 4 + qo;
                const uint4 v = *(const uint4*)&L.Ep[w * 16 + l15o][c * 8];
                const int n  = n0 + w * 64 + j * 16 + l15o;
                const int hh = n >> 6;
                const int jt = ((m0 & 2047) >> 6) + c3;
                const int o  = j * 2 + k1;
                const size_t off =
                    ((((size_t)(bb * Hn + hh) * 32 + jt) * 8 + o) * 64 + qo * 16 + l15o) * 8;
                *(uint4*)(VwT + off) = v;
            }
        }
    }
}

// ---------------------------------------------------------------------------
// Final GEMM: tile 128(m) x 64(n), BK=64, grid 512 (2 blocks/CU). A from the
// CHUNK-TILED attn output (1KB contiguous DMAs), B from chunk-tiled Wt.
// Per wave per tile: 4 A + 2 B gl_lds = 6; depth-2, counted vmcnt(6).
// LDS: 2 x (16KB A + 8KB B) = 48 KB.
// ---------------------------------------------------------------------------
__global__ __launch_bounds__(256) void gemm_final(
    const u16* __restrict__ A, const u16* __restrict__ Bt,
    const float* __restrict__ bias, float* __restrict__ out)
{
    __shared__ __align__(16) u16 Abf[2][16 * 512];  // 2 x 16 KB
    __shared__ __align__(16) u16 Bbf[2][8 * 512];   // 2 x 8 KB

    const int f = blockIdx.x;                // 512 blocks
    const int xcd = f & 7, q = f >> 3;       // q in [0,64)
    const int y = xcd * 4 + (q >> 4);        // [0,32) m-tile
    const int x = q & 15;                    // [0,16) n-tile
    const int m0 = y * 128, n0 = x * 64;
    const int bb = y >> 4;
    const int jtb = (y & 15) * 2;            // jt base within head

    const int t = threadIdx.x;
    const int lane = t & 63, wave = t >> 6;
    const int quad = lane >> 4, l15 = lane & 15;
    const int wm = wave >> 1, wn = wave & 1;

    // A: chunks c = wave*4+s; c = (jt2*4+sub16)*2 + dsub
    const u16* baseA[4];
#pragma unroll
    for (int s = 0; s < 4; s++) {
        const int c = wave * 4 + s;
        const int g = c >> 1, dsub = c & 1;
        const int jt2 = g >> 2, sub16 = g & 3;
        baseA[s] = A + (((size_t)(bb * Hn) * 32 + jtb + jt2) * 8 + (sub16 * 2 + dsub)) * 512
                     + lane * 8;
    }
    // B: chunks cb = wave*2+s; cb = os*2 + ksub; Wt z=3 slab addressing (64-wide n)
    const u16* baseB[2];
#pragma unroll
    for (int s = 0; s < 2; s++) {
        const int cb = wave * 2 + s;
        const int os = cb >> 1, ksub = cb & 1;
        baseB[s] = Bt + (((size_t)(x >> 1) * 32 + ksub) * 8 + ((x & 1) * 4 + os)) * 512
                      + lane * 8;
    }

    auto STAGE = [&](int tt, int buf) {
#pragma unroll
        for (int s = 0; s < 4; s++)
            gl_lds16(baseA[s] + (size_t)tt * 131072, &Abf[buf][(wave * 4 + s) * 512]);
#pragma unroll
        for (int s = 0; s < 2; s++)
            gl_lds16(baseB[s] + (size_t)tt * 8192, &Bbf[buf][(wave * 2 + s) * 512]);
    };

    f32x4 acc[4][2];
#pragma unroll
    for (int i = 0; i < 4; i++)
#pragma unroll
        for (int j = 0; j < 2; j++) acc[i][j] = (f32x4){0.f, 0.f, 0.f, 0.f};

    const int NT = 16;  // one k-block (64) per head
    STAGE(0, 0);
    STAGE(1, 1);

    for (int tt = 0; tt < NT; ++tt) {
        const int buf = tt & 1;
        if (tt < NT - 1) asm volatile("s_waitcnt vmcnt(6)" ::: "memory");
        else             asm volatile("s_waitcnt vmcnt(0)" ::: "memory");
        barrier_nodrain();

        bf16x8 a[4][2], b[2][2];
#pragma unroll
        for (int i = 0; i < 4; i++)
#pragma unroll
            for (int ks = 0; ks < 2; ks++) {
                const int c = (wm * 4 + i) * 2 + ks;
                a[i][ks] = ldfrag(&Abf[buf][c * 512 + (quad * 16 + l15) * 8]);
            }
#pragma unroll
        for (int j = 0; j < 2; j++)
#pragma unroll
            for (int ks = 0; ks < 2; ks++) {
                const int cb = (wn * 2 + j) * 2 + ks;
                b[j][ks] = ldfrag(&Bbf[buf][cb * 512 + (quad * 16 + l15) * 8]);
            }
#pragma unroll
        for (int i = 0; i < 4; i++)
#pragma unroll
            for (int j = 0; j < 2; j++)
#pragma unroll
                for (int ks = 0; ks < 2; ks++)
                    acc[i][j] = __builtin_amdgcn_mfma_f32_16x16x32_bf16(
                        a[i][ks], b[j][ks], acc[i][j], 0, 0, 0);

        asm volatile("s_waitcnt lgkmcnt(0)" ::: "memory");
        barrier_nodrain();
        if (tt + 2 < NT) STAGE(tt + 2, buf);
    }

    float bv[2];
#pragma unroll
    for (int j = 0; j < 2; j++) bv[j] = bias[n0 + wn * 32 + j * 16 + l15];

#pragma unroll
    for (int i = 0; i < 4; i++)
#pragma unroll
        for (int j = 0; j < 2; j++) {
            const int n = n0 + wn * 32 + j * 16 + l15;
#pragma unroll
            for (int r = 0; r < 4; r++) {
                const int m = m0 + wm * 64 + i * 16 + quad * 4 + r;
                out[(size_t)m * DIMn + n] = acc[i][j][r] + bv[j];
            }
        }
}

// ---------------------------------------------------------------------------
// MFMA flash attention. K/V chunk-tiled staging, depth-2 vmcnt(4) pipeline.
// Manual-RNE f2bf in the softmax chain (the native cast's cmp/cndmask pattern
// was the round-5 regression suspect). Tile loop unrolled 8x so the mask
// shift and Ps addressing are compile-time. Epilogue writes CANONICAL CHUNK
// layout consumed by gemm_final (aliases the Q slab, alias-safe).
// ---------------------------------------------------------------------------
__global__ __launch_bounds__(256) void attn_mfma(
    const u16* __restrict__ Qw, const u16* __restrict__ Kw,
    const u16* __restrict__ VwT, const int* __restrict__ mask,
    const int* __restrict__ tstat, u16* __restrict__ Aw)
{
    __shared__ __align__(16) u16 Kbf[2][32 * 128];  // 2 x 8 KB chunked
    __shared__ __align__(16) u16 Vbf[2][32 * 128];  // 2 x 8 KB chunked
    __shared__ __align__(16) u16 Ps[64 * 64];       // 8 KB, XOR-swizzled in loop

    const int f = blockIdx.x;
    const int xcd = f & 7, q = f >> 3;
    const int p = xcd * 4 + (q >> 5);
    const int qt = q & 31;
    const int b = p >> 4, h = p & 15;
    const int q0 = qt * 64;

    const int t = threadIdx.x;
    const int lane = t & 63, wave = t >> 6;
    const int quad = lane >> 4, l15 = lane & 15;
    const bool use_mask = (tstat[0] != 0);
    const size_t slab = (size_t)(b * Hn + h) * Sn * DHn;

    // Tiled K/V staging bases: head slab = 32 tiles x 8 chunks x 512 u16
    const size_t hbase = (size_t)(b * Hn + h) * 32 * 8 * 512;
    const u16* baseK[2];
    const u16* baseV[2];
#pragma unroll
    for (int s = 0; s < 2; s++) {
        const int o = wave * 2 + s;
        baseK[s] = Kw  + hbase + (size_t)o * 512 + lane * 8;
        baseV[s] = VwT + hbase + (size_t)o * 512 + lane * 8;
    }

    // ---- prologue: stage full 8 KB mask into Kbf[0] with plain loads ----
    {
        const int4* msrc4 = (const int4*)(mask + (size_t)b * Sn);  // 512 int4
        int4* mdst4 = (int4*)&Kbf[0][0];
        mdst4[t]       = msrc4[t];
        mdst4[t + 256] = msrc4[t + 256];
    }
    bf16x8 aq[2];
#pragma unroll
    for (int ks = 0; ks < 2; ks++) {
        union { uint4 u; bf16x8 v; } xx;
        xx.u = *(const uint4*)(Qw + slab + (size_t)(q0 + wave * 16 + l15) * DHn + ks * 32 + quad * 8);
        aq[ks] = xx.v;
    }
    __syncthreads();  // Q in regs, full mask visible in LDS

    // ---- pack this lane's mask bits: bit k = (mask[k*16 + l15] != 0) ----
    u32 mw0 = 0, mw1 = 0, mw2 = 0, mw3 = 0;
    {
        const int* ml = (const int*)&Kbf[0][0];
#pragma unroll
        for (int k = 0; k < 128; k++) {
            const u32 bit = (ml[k * 16 + l15] != 0) ? 1u : 0u;
            if (k < 32)      mw0 |= bit << k;
            else if (k < 64) mw1 |= bit << (k - 32);
            else if (k < 96) mw2 |= bit << (k - 64);
            else             mw3 |= bit << (k - 96);
        }
    }
    __syncthreads();  // pack reads retired before Kbf[0] reuse

    auto STAGE = [&](int tt, int buf) {
#pragma unroll
        for (int s = 0; s < 2; s++) {
            gl_lds16(baseK[s] + (size_t)tt * 4096, &Kbf[buf][(wave * 8 + s * 4) * 128]);
            gl_lds16(baseV[s] + (size_t)tt * 4096, &Vbf[buf][(wave * 8 + s * 4) * 128]);
        }
    };

    float lsum[4] = {0.f, 0.f, 0.f, 0.f};
    f32x4 O[4];
#pragma unroll
    for (int dt = 0; dt < 4; dt++) O[dt] = (f32x4){0.f, 0.f, 0.f, 0.f};

    const int NT = Sn / 64;  // 32
    STAGE(0, 0);
    STAGE(1, 1);

#pragma unroll 8
    for (int tt = 0; tt < NT; ++tt) {
        const int buf = tt & 1;
        if (tt < NT - 1) asm volatile("s_waitcnt vmcnt(4)" ::: "memory");
        else             asm volatile("s_waitcnt vmcnt(0)" ::: "memory");
        barrier_nodrain();

        // ---- S = Q K^T ----
        f32x4 s[4];
#pragma unroll
        for (int ct = 0; ct < 4; ct++) s[ct] = (f32x4){0.f, 0.f, 0.f, 0.f};
#pragma unroll
        for (int ct = 0; ct < 4; ct++)
#pragma unroll
            for (int ks = 0; ks < 2; ks++) {
                const bf16x8 bk = ldfrag(&Kbf[buf][(ct * 8 + ks * 4 + quad) * 128 + l15 * 8]);
                s[ct] = __builtin_amdgcn_mfma_f32_16x16x32_bf16(aq[ks], bk, s[ct], 0, 0, 0);
            }

        // ---- mask bias for this tile: k = tt*4 + ct ----
        const int wsel = tt >> 3;
        const u32 cw = (wsel == 0) ? mw0 : (wsel == 1) ? mw1 : (wsel == 2) ? mw2 : mw3;
        const int sh = (tt & 7) * 4;
        float badd[4];
#pragma unroll
        for (int ct = 0; ct < 4; ct++)
            badd[ct] = (!use_mask || ((cw >> (sh + ct)) & 1u)) ? 0.0f : -1e9f;

        // ---- P = exp(s/64 + badd); accumulate l; stash P ----
#pragma unroll
        for (int ct = 0; ct < 4; ct++)
#pragma unroll
            for (int r = 0; r < 4; r++) {
                const float pp = __expf(fmaf(s[ct][r], 1.0f / 64.0f, badd[ct]));
                lsum[r] += pp;
                const int prow = wave * 16 + quad * 4 + r;
                Ps[prow * 64 + ((ct * 16 + l15) ^ ((prow & 7) << 3))] = f2bf(pp);
            }
        asm volatile("s_waitcnt lgkmcnt(0)" ::: "memory");  // wave-private band

        // ---- O += P V ----
        bf16x8 pa[2];
        const int rrow = wave * 16 + l15;
#pragma unroll
        for (int kc = 0; kc < 2; kc++)
            pa[kc] = ldfrag(&Ps[rrow * 64 + ((kc * 32 + quad * 8) ^ ((l15 & 7) << 3))]);
#pragma unroll
        for (int dt = 0; dt < 4; dt++)
#pragma unroll
            for (int kc = 0; kc < 2; kc++) {
                const bf16x8 bvv = ldfrag(&Vbf[buf][(dt * 8 + kc * 4 + quad) * 128 + l15 * 8]);
                O[dt] = __builtin_amdgcn_mfma_f32_16x16x32_bf16(pa[kc], bvv, O[dt], 0, 0, 0);
            }

        asm volatile("s_waitcnt lgkmcnt(0)" ::: "memory");
        barrier_nodrain();
        if (tt + 2 < NT) STAGE(tt + 2, buf);
    }

    // ---- reduce l across the 16 column-lanes ----
#pragma unroll
    for (int r = 0; r < 4; r++) {
#pragma unroll
        for (int off = 1; off < 16; off <<= 1) lsum[r] += __shfl_xor(lsum[r], off);
    }
    float linv[4];
#pragma unroll
    for (int r = 0; r < 4; r++) linv[r] = 1.0f / fmaxf(lsum[r], 1e-30f);

    // ---- epilogue: restage O in Ps (plain), then store CHUNK-TILED ----
    __syncthreads();
#pragma unroll
    for (int r = 0; r < 4; r++)
#pragma unroll
        for (int dt = 0; dt < 4; dt++)
            Ps[(wave * 16 + quad * 4 + r) * 64 + dt * 16 + l15] = f2bf(O[dt][r] * linv[r]);
    __syncthreads();
    const size_t cbase = ((size_t)(b * Hn + h) * 32 + qt) * 4096;  // == Q slab (8KB)
#pragma unroll
    for (int e2 = 0; e2 < 2; e2++) {
        const int tid = t + 256 * e2;
        const int row = tid >> 3, cg = tid & 7;
        const int sub16 = row >> 4, dsub = cg >> 2, quadk = cg & 3;
        const uint4 v = *(const uint4*)&Ps[row * 64 + cg * 8];
        *(uint4*)(Aw + cbase + (size_t)(sub16 * 2 + dsub) * 512
                  + (quadk * 16 + (row & 15)) * 8) = v;
    }
}

// ---------------------------------------------------------------------------
extern "C" void kernel_launch(void* const* d_in, const int* in_sizes, int n_in,
                              void* d_out, int out_size, void* d_ws, size_t ws_size,
                              hipStream_t stream) {
    const float* query = (const float*)d_in[0];
    const float* key   = (const float*)d_in[1];
    const float* value = (const float*)d_in[2];
    const int*   pmask = (const int*)d_in[3];
    const int*   tstat = (const int*)d_in[4];
    const float* Wq  = (const float*)d_in[5];
    const float* bq  = (const float*)d_in[6];
    const float* Wk  = (const float*)d_in[7];
    const float* bk  = (const float*)d_in[8];
    const float* Wv  = (const float*)d_in[9];
    const float* bv  = (const float*)d_in[10];
    const float* Wf  = (const float*)d_in[11];
    const float* bfb = (const float*)d_in[12];
    float* outp = (float*)d_out;

    // ws (32 MB): Qw(8, attn-out alias) | Kw tiled(8) | VwT tiled(8) | Wt tiled 4x2MB(8)
    const size_t NT = (size_t)Bn * Sn * DIMn;
    u16* Qw  = (u16*)d_ws;
    u16* Kw  = Qw + NT;
    u16* VwT = Kw + NT;
    u16* Wt  = VwT + NT;
    const size_t WSZ = (size_t)DIMn * DIMn;

    prep_weights<<<dim3(16, 16, 4), 256, 0, stream>>>(Wq, Wk, Wv, Wf, Wt);

    gemm_qkv<<<768, 256, 0, stream>>>(query, key, value, Wt, bq, bk, bv, Qw, Kw, VwT);

    attn_mfma<<<1024, 256, 0, stream>>>(Qw, Kw, VwT, pmask, tstat, Qw);

    gemm_final<<<512, 256, 0, stream>>>(Qw, Wt + 3 * WSZ, bfb, outp);
}

// Round 9
// 246.852 us; speedup vs baseline: 1.1262x; 1.0869x over previous
//
#include <hip/hip_runtime.h>

// Problem: B=2, S=2048, DIM=1024, H=16, DH=64. I/O fp32; internals bf16 MFMA.
#define Bn   2
#define Sn   2048
#define DIMn 1024
#define Hn   16
#define DHn  64

typedef unsigned short u16;
typedef unsigned int   u32;

typedef __attribute__((ext_vector_type(8))) __bf16 bf16x8;
typedef __attribute__((ext_vector_type(4))) __bf16 bf16x4;
typedef __attribute__((ext_vector_type(8))) float  f32x8v;
typedef __attribute__((ext_vector_type(4))) float  f32x4;

// manual RNE f32->bf16 (3-4 VALU ops). Bit-identical to RNE cast on non-NaN.
__device__ __forceinline__ u16 f2bf(float f) {
    union { float f; u32 u; } v; v.f = f;
    u32 r = v.u + 0x7fffu + ((v.u >> 16) & 1u);  // RNE
    return (u16)(r >> 16);
}
__device__ __forceinline__ bf16x8 ldfrag(const u16* p) {
    union { uint4 u; bf16x8 v; } x;
    x.u = *(const uint4*)p;
    return x.v;
}
__device__ __forceinline__ uint4 pack8(const u16 h[8]) {
    uint4 r;
    r.x = (u32)h[0] | ((u32)h[1] << 16);
    r.y = (u32)h[2] | ((u32)h[3] << 16);
    r.z = (u32)h[4] | ((u32)h[5] << 16);
    r.w = (u32)h[6] | ((u32)h[7] << 16);
    return r;
}
// async 16B global->LDS: lds dest = wave-uniform base + lane*16; global src PER-LANE
__device__ __forceinline__ void gl_lds16(const void* g, void* l) {
    __builtin_amdgcn_global_load_lds(
        (const __attribute__((address_space(1))) void*)g,
        (__attribute__((address_space(3))) void*)l, 16, 0, 0);
}
// raw barrier with compiler-level memory fences on both sides (no vmcnt drain)
__device__ __forceinline__ void barrier_nodrain() {
    asm volatile("" ::: "memory");
    __builtin_amdgcn_s_barrier();
    asm volatile("" ::: "memory");
}

// ---------------------------------------------------------------------------
// Prep: transpose+convert fp32 weights [k][n] -> bf16 CHUNK-TILED Wt.
// Layout: off(z,X,T,o,lane=quad*16+l15,e) =
//   ((((z*8+X)*32+T)*8+o)*64 + quad*16+l15)*8 + e
// holding element (n = X*128+o*16+l15, k = T*32+quad*8+e).
// ---------------------------------------------------------------------------
__global__ __launch_bounds__(256) void prep_weights(
    const float* __restrict__ Wq, const float* __restrict__ Wk,
    const float* __restrict__ Wv, const float* __restrict__ Wf,
    u16* __restrict__ Wt)
{
    __shared__ __align__(16) float tile[64][68];
    const float* W = (blockIdx.z == 0) ? Wq : (blockIdx.z == 1) ? Wk
                   : (blockIdx.z == 2) ? Wv : Wf;
    const int t = threadIdx.x;
    const int n0 = blockIdx.x * 64, k0 = blockIdx.y * 64;
    const int rr = t >> 4, cc = (t & 15) * 4;
#pragma unroll
    for (int i = 0; i < 4; i++)
        *(float4*)&tile[rr + 16 * i][cc] =
            *(const float4*)(W + (size_t)(k0 + rr + 16 * i) * DIMn + n0 + cc);
    __syncthreads();
#pragma unroll
    for (int e = 0; e < 2; e++) {
        const int ci = 2 * t + e;
        const int nn = ci >> 3, kc = ci & 7;
        const int n = n0 + nn, k = k0 + kc * 8;
        u16 h[8];
#pragma unroll
        for (int j = 0; j < 8; j++) h[j] = f2bf(tile[kc * 8 + j][nn]);
        const int X = n >> 7, o = (n >> 4) & 7, l15 = n & 15;
        const int T = k >> 5, quad = (k >> 3) & 3;
        const size_t off =
            ((((size_t)(blockIdx.z * 8 + X) * 32 + T) * 8 + o) * 64 + quad * 16 + l15) * 8;
        *(uint4*)(Wt + off) = pack8(h);
    }
}

// ---------------------------------------------------------------------------
// Fused QKV GEMM. A reg-staged with FULL-LINE loads (8 rows x 128B per
// instruction; lane = r8*8+c8), in-register cvt, b64 ds_write into canonical
// chunk layout. B via gl_lds from chunk-tiled Wt. Depth-2, counted vmcnt(6).
// ---------------------------------------------------------------------------
__global__ __launch_bounds__(256) void gemm_qkv(
    const float* __restrict__ Aq, const float* __restrict__ Ak,
    const float* __restrict__ Av, const u16* __restrict__ Wt,
    const float* __restrict__ bqp, const float* __restrict__ bkp,
    const float* __restrict__ bvp, u16* __restrict__ Qw,
    u16* __restrict__ Kw, u16* __restrict__ VwT)
{
    __shared__ union {
        struct { __align__(16) u16 Abf[2][4096];     // 2 x 8 KB canonical chunks
                 __align__(16) u16 Bbf[2][4096]; } s;  // 2 x 8 KB canonical chunks
        __align__(16) u16 Ep[32][144];               // epilogue staging
    } L;

    // ---- XCD-aware swizzle: f = xcd + 8*(x + 8*(yi + 4*z)) ----
    const int f = blockIdx.x;
    const int xcd = f & 7;
    const int q = f >> 3;
    const int z = q >> 5;
    const int rem = q & 31;
    const int yi = rem >> 3, x = rem & 7;
    const int y = xcd * 4 + yi;
    const int m0 = y * 128, n0 = x * 128;

    const float* A    = (z == 0) ? Aq  : (z == 1) ? Ak  : Av;
    const float* bias = (z == 0) ? bqp : (z == 1) ? bkp : bvp;

    const int t = threadIdx.x;
    const int lane = t & 63, wave = t >> 6;
    const int quad = lane >> 4, l15 = lane & 15;
    const int wm = wave >> 1, wn = wave & 1;
    const int r8 = lane >> 3, c8 = lane & 7;

    // A staging: chunk o = wave*2+s (16 rows x 32 k fp32). Instr (s,h): lane
    // reads row m0+o*16+r8+h*8, cols c8*4..+4 -> 8 rows x 128B FULL LINES.
    const float* baseA[2];
#pragma unroll
    for (int s = 0; s < 2; s++)
        baseA[s] = A + (size_t)(m0 + (wave * 2 + s) * 16 + r8) * DIMn + c8 * 4;
    const u16* baseB[2];
#pragma unroll
    for (int s = 0; s < 2; s++)
        baseB[s] = Wt + ((size_t)((z * 8 + x) * 32) * 8 + (wave * 2 + s)) * 512 + lane * 8;

    auto LOADA = [&](int tt, uint4 (&ar)[4]) {
#pragma unroll
        for (int s = 0; s < 2; s++)
#pragma unroll
            for (int h = 0; h < 2; h++)
                ar[2 * s + h] = *(const uint4*)(baseA[s] + (size_t)h * 8 * DIMn + tt * 32);
    };
    auto STAGEB = [&](int tt, int buf) {
#pragma unroll
        for (int s = 0; s < 2; s++)
            gl_lds16(baseB[s] + (size_t)tt * 4096, &L.s.Bbf[buf][(wave * 2 + s) * 512]);
    };
    // canonical chunk addr for element (row=r8+h*8, k=c8*4+e):
    //   o*512 + ((k>>3)*16 + row)*8 + (k&7) -> contiguous 4 u16 = b64 write
    auto CVTWRITE = [&](uint4 (&ar)[4], int buf) {
#pragma unroll
        for (int s = 0; s < 2; s++)
#pragma unroll
            for (int h = 0; h < 2; h++) {
                union { uint4 u; f32x4 f; } cv; cv.u = ar[2 * s + h];
                union { bf16x4 v; uint2 u; } hv;
                hv.v = __builtin_convertvector(cv.f, bf16x4);
                *(uint2*)&L.s.Abf[buf][(wave * 2 + s) * 512 +
                    ((c8 >> 1) * 16 + r8 + h * 8) * 8 + (c8 & 1) * 4] = hv.u;
            }
    };

    f32x4 acc[4][4];
#pragma unroll
    for (int i = 0; i < 4; i++)
#pragma unroll
        for (int j = 0; j < 4; j++) acc[i][j] = (f32x4){0.f, 0.f, 0.f, 0.f};

    const int NT = DIMn / 32;  // 32
    uint4 ra[4], rb[4];        // static double-buffered A regs (rule #20)
    LOADA(0, ra); STAGEB(0, 0);
    LOADA(1, rb); STAGEB(1, 1);

    auto ITER = [&](int tt, uint4 (&ar)[4], int buf) {
        if (tt < NT - 1) asm volatile("s_waitcnt vmcnt(6)" ::: "memory");
        else             asm volatile("s_waitcnt vmcnt(0)" ::: "memory");
        CVTWRITE(ar, buf);
        asm volatile("s_waitcnt lgkmcnt(0)" ::: "memory");
        barrier_nodrain();

        bf16x8 a[4], b[4];
#pragma unroll
        for (int i = 0; i < 4; i++)
            a[i] = ldfrag(&L.s.Abf[buf][((wm * 4 + i) * 4 + quad) * 128 + l15 * 8]);
#pragma unroll
        for (int j = 0; j < 4; j++)
            b[j] = ldfrag(&L.s.Bbf[buf][((wn * 4 + j) * 4 + quad) * 128 + l15 * 8]);
#pragma unroll
        for (int i = 0; i < 4; i++)
#pragma unroll
            for (int j = 0; j < 4; j++)
                acc[i][j] = __builtin_amdgcn_mfma_f32_16x16x32_bf16(a[i], b[j], acc[i][j], 0, 0, 0);

        asm volatile("s_waitcnt lgkmcnt(0)" ::: "memory");
        barrier_nodrain();
        if (tt + 2 < NT) { LOADA(tt + 2, ar); STAGEB(tt + 2, buf); }
    };
    for (int tt = 0; tt < NT; tt += 2) { ITER(tt, ra, 0); ITER(tt + 1, rb, 1); }

    float bv[4];
#pragma unroll
    for (int j = 0; j < 4; j++) bv[j] = bias[n0 + wn * 64 + j * 16 + l15];

    const int bb = y >> 4;

    if (z == 0) {
        // ---- Q: [b,h,s,d], phase over i ----
#pragma unroll
    for (int i = 0; i < 4; i++) {
            __syncthreads();
#pragma unroll
            for (int j = 0; j < 4; j++)
#pragma unroll
                for (int r = 0; r < 4; r++)
                    L.Ep[wm * 16 + quad * 4 + r][wn * 64 + j * 16 + l15] =
                        f2bf(acc[i][j][r] + bv[j]);
            __syncthreads();
#pragma unroll
            for (int e = 0; e < 2; e++) {
                const int ci = t + 256 * e;
                const int row = ci >> 4, c = ci & 15;
                const uint4 v = *(const uint4*)&L.Ep[row][c * 8];
                const int m = m0 + (row >> 4) * 64 + i * 16 + (row & 15);
                const int ss = m & 2047;
                const int n = n0 + c * 8;
                const int hh = n >> 6, dd = n & 63;
                *(uint4*)(Qw + ((size_t)(bb * Hn + hh) * Sn + ss) * DHn + dd) = v;
            }
        }
    } else if (z == 1) {
        // ---- K: attn-chunk-tiled; wave-contiguous 1KB stores ----
#pragma unroll
        for (int i = 0; i < 4; i++) {
            __syncthreads();
#pragma unroll
            for (int j = 0; j < 4; j++)
#pragma unroll
                for (int r = 0; r < 4; r++)
                    L.Ep[wm * 16 + quad * 4 + r][wn * 64 + j * 16 + l15] =
                        f2bf(acc[i][j][r] + bv[j]);
            __syncthreads();
#pragma unroll
            for (int e2 = 0; e2 < 2; e2++) {
                const int tid = t + 256 * e2;
                const int l15o = tid & 15;
                const int qo   = (tid >> 4) & 3;
                const int k1   = (tid >> 6) & 1;
                const int c3   = (tid >> 7) & 1;
                const int w    = (tid >> 8) & 1;
                const int c    = c3 * 8 + k1 * 4 + qo;
                const uint4 v = *(const uint4*)&L.Ep[w * 16 + l15o][c * 8];
                const int ss = (m0 & 2047) + w * 64 + i * 16 + l15o;
                const int hh = (n0 + c * 8) >> 6;
                const int jt = ss >> 6;
                const int o  = i * 2 + k1;
                const size_t off =
                    ((((size_t)(bb * Hn + hh) * 32 + jt) * 8 + o) * 64 + qo * 16 + l15o) * 8;
                *(uint4*)(Kw + off) = v;
            }
        }
    } else {
        // ---- V: attn-chunk-tiled (transposed fill), phase over j ----
#pragma unroll
        for (int j = 0; j < 4; j++) {
            __syncthreads();
#pragma unroll
            for (int i = 0; i < 4; i++) {
                u16 h4[4];
#pragma unroll
                for (int r = 0; r < 4; r++) h4[r] = f2bf(acc[i][j][r] + bv[j]);
                uint2 pk;
                pk.x = (u32)h4[0] | ((u32)h4[1] << 16);
                pk.y = (u32)h4[2] | ((u32)h4[3] << 16);
                *(uint2*)&L.Ep[wn * 16 + l15][wm * 64 + i * 16 + quad * 4] = pk;
            }
            __syncthreads();
#pragma unroll
            for (int e2 = 0; e2 < 2; e2++) {
                const int tid = t + 256 * e2;
                const int l15o = tid & 15;
                const int qo   = (tid >> 4) & 3;
                const int k1   = (tid >> 6) & 1;
                const int c3   = (tid >> 7) & 1;
                const int w    = (tid >> 8) & 1;
                const int c    = c3 * 8 + k1 * 4 + qo;
                const uint4 v = *(const uint4*)&L.Ep[w * 16 + l15o][c * 8];
                const int n  = n0 + w * 64 + j * 16 + l15o;
                const int hh = n >> 6;
                const int jt = ((m0 & 2047) >> 6) + c3;
                const int o  = j * 2 + k1;
                const size_t off =
                    ((((size_t)(bb * Hn + hh) * 32 + jt) * 8 + o) * 64 + qo * 16 + l15o) * 8;
                *(uint4*)(VwT + off) = v;
            }
        }
    }
}

// ---------------------------------------------------------------------------
// Final GEMM: tile 128(m) x 64(n), BK=64, grid 512 (2 blocks/CU). DEPTH-3
// pipeline (NT=16 is short; one more tile in flight). A from chunk-tiled attn
// output, B from chunk-tiled Wt. 6 ops/wave/tile -> vmcnt(12)/(6)/(0).
// LDS: 3 x (16KB A + 8KB B) = 72 KB -> still 2 blocks/CU.
// ---------------------------------------------------------------------------
__global__ __launch_bounds__(256) void gemm_final(
    const u16* __restrict__ A, const u16* __restrict__ Bt,
    const float* __restrict__ bias, float* __restrict__ out)
{
    __shared__ __align__(16) u16 Abf[3][16 * 512];  // 3 x 16 KB
    __shared__ __align__(16) u16 Bbf[3][8 * 512];   // 3 x 8 KB

    const int f = blockIdx.x;                // 512 blocks
    const int xcd = f & 7, q = f >> 3;       // q in [0,64)
    const int y = xcd * 4 + (q >> 4);        // [0,32) m-tile
    const int x = q & 15;                    // [0,16) n-tile
    const int m0 = y * 128, n0 = x * 64;
    const int bb = y >> 4;
    const int jtb = (y & 15) * 2;            // jt base within head

    const int t = threadIdx.x;
    const int lane = t & 63, wave = t >> 6;
    const int quad = lane >> 4, l15 = lane & 15;
    const int wm = wave >> 1, wn = wave & 1;

    // A: chunks c = wave*4+s; c = (jt2*4+sub16)*2 + dsub
    const u16* baseA[4];
#pragma unroll
    for (int s = 0; s < 4; s++) {
        const int c = wave * 4 + s;
        const int g = c >> 1, dsub = c & 1;
        const int jt2 = g >> 2, sub16 = g & 3;
        baseA[s] = A + (((size_t)(bb * Hn) * 32 + jtb + jt2) * 8 + (sub16 * 2 + dsub)) * 512
                     + lane * 8;
    }
    // B: chunks cb = wave*2+s; cb = os*2 + ksub; Wt z=3 slab addressing (64-wide n)
    const u16* baseB[2];
#pragma unroll
    for (int s = 0; s < 2; s++) {
        const int cb = wave * 2 + s;
        const int os = cb >> 1, ksub = cb & 1;
        baseB[s] = Bt + (((size_t)(x >> 1) * 32 + ksub) * 8 + ((x & 1) * 4 + os)) * 512
                      + lane * 8;
    }

    auto STAGE = [&](int tt, int buf) {
#pragma unroll
        for (int s = 0; s < 4; s++)
            gl_lds16(baseA[s] + (size_t)tt * 131072, &Abf[buf][(wave * 4 + s) * 512]);
#pragma unroll
        for (int s = 0; s < 2; s++)
            gl_lds16(baseB[s] + (size_t)tt * 8192, &Bbf[buf][(wave * 2 + s) * 512]);
    };

    f32x4 acc[4][2];
#pragma unroll
    for (int i = 0; i < 4; i++)
#pragma unroll
        for (int j = 0; j < 2; j++) acc[i][j] = (f32x4){0.f, 0.f, 0.f, 0.f};

    const int NT = 16;  // one k-block (64) per head
    STAGE(0, 0);
    STAGE(1, 1);
    STAGE(2, 2);

    int buf = 0;
    for (int tt = 0; tt < NT; ++tt) {
        if (tt < NT - 2)       asm volatile("s_waitcnt vmcnt(12)" ::: "memory");
        else if (tt == NT - 2) asm volatile("s_waitcnt vmcnt(6)" ::: "memory");
        else                   asm volatile("s_waitcnt vmcnt(0)" ::: "memory");
        barrier_nodrain();

        bf16x8 a[4][2], b[2][2];
#pragma unroll
        for (int i = 0; i < 4; i++)
#pragma unroll
            for (int ks = 0; ks < 2; ks++) {
                const int c = (wm * 4 + i) * 2 + ks;
                a[i][ks] = ldfrag(&Abf[buf][c * 512 + (quad * 16 + l15) * 8]);
            }
#pragma unroll
        for (int j = 0; j < 2; j++)
#pragma unroll
            for (int ks = 0; ks < 2; ks++) {
                const int cb = (wn * 2 + j) * 2 + ks;
                b[j][ks] = ldfrag(&Bbf[buf][cb * 512 + (quad * 16 + l15) * 8]);
            }
#pragma unroll
        for (int i = 0; i < 4; i++)
#pragma unroll
            for (int j = 0; j < 2; j++)
#pragma unroll
                for (int ks = 0; ks < 2; ks++)
                    acc[i][j] = __builtin_amdgcn_mfma_f32_16x16x32_bf16(
                        a[i][ks], b[j][ks], acc[i][j], 0, 0, 0);

        asm volatile("s_waitcnt lgkmcnt(0)" ::: "memory");
        barrier_nodrain();
        if (tt + 3 < NT) STAGE(tt + 3, buf);
        buf = (buf == 2) ? 0 : buf + 1;
    }

    float bv[2];
#pragma unroll
    for (int j = 0; j < 2; j++) bv[j] = bias[n0 + wn * 32 + j * 16 + l15];

#pragma unroll
    for (int i = 0; i < 4; i++)
#pragma unroll
        for (int j = 0; j < 2; j++) {
            const int n = n0 + wn * 32 + j * 16 + l15;
#pragma unroll
            for (int r = 0; r < 4; r++) {
                const int m = m0 + wm * 64 + i * 16 + quad * 4 + r;
                out[(size_t)m * DIMn + n] = acc[i][j][r] + bv[j];
            }
        }
}

// ---------------------------------------------------------------------------
// MFMA flash attention. K/V chunk-tiled staging, depth-2 vmcnt(4) pipeline.
// kc-SPLIT: softmax(ct2-3) is placed between pa0 and PV(kc0) so the exp/VALU
// chain co-issues with the MFMA pipe. exp via v_exp_f32 (exp2) with folded
// constants. Epilogue writes CANONICAL CHUNK layout (aliases Q slab).
// ---------------------------------------------------------------------------
__global__ __launch_bounds__(256) void attn_mfma(
    const u16* __restrict__ Qw, const u16* __restrict__ Kw,
    const u16* __restrict__ VwT, const int* __restrict__ mask,
    const int* __restrict__ tstat, u16* __restrict__ Aw)
{
    __shared__ __align__(16) u16 Kbf[2][32 * 128];  // 2 x 8 KB chunked
    __shared__ __align__(16) u16 Vbf[2][32 * 128];  // 2 x 8 KB chunked
    __shared__ __align__(16) u16 Ps[64 * 64];       // 8 KB, XOR-swizzled in loop

    const int f = blockIdx.x;
    const int xcd = f & 7, q = f >> 3;
    const int p = xcd * 4 + (q >> 5);
    const int qt = q & 31;
    const int b = p >> 4, h = p & 15;
    const int q0 = qt * 64;

    const int t = threadIdx.x;
    const int lane = t & 63, wave = t >> 6;
    const int quad = lane >> 4, l15 = lane & 15;
    const bool use_mask = (tstat[0] != 0);
    const size_t slab = (size_t)(b * Hn + h) * Sn * DHn;

    // Tiled K/V staging bases: head slab = 32 tiles x 8 chunks x 512 u16
    const size_t hbase = (size_t)(b * Hn + h) * 32 * 8 * 512;
    const u16* baseK[2];
    const u16* baseV[2];
#pragma unroll
    for (int s = 0; s < 2; s++) {
        const int o = wave * 2 + s;
        baseK[s] = Kw  + hbase + (size_t)o * 512 + lane * 8;
        baseV[s] = VwT + hbase + (size_t)o * 512 + lane * 8;
    }

    // ---- prologue: stage full 8 KB mask into Kbf[0] with plain loads ----
    {
        const int4* msrc4 = (const int4*)(mask + (size_t)b * Sn);  // 512 int4
        int4* mdst4 = (int4*)&Kbf[0][0];
        mdst4[t]       = msrc4[t];
        mdst4[t + 256] = msrc4[t + 256];
    }
    bf16x8 aq[2];
#pragma unroll
    for (int ks = 0; ks < 2; ks++) {
        union { uint4 u; bf16x8 v; } xx;
        xx.u = *(const uint4*)(Qw + slab + (size_t)(q0 + wave * 16 + l15) * DHn + ks * 32 + quad * 8);
        aq[ks] = xx.v;
    }
    __syncthreads();  // Q in regs, full mask visible in LDS

    // ---- pack this lane's mask bits: bit k = (mask[k*16 + l15] != 0) ----
    u32 mw0 = 0, mw1 = 0, mw2 = 0, mw3 = 0;
    {
        const int* ml = (const int*)&Kbf[0][0];
#pragma unroll
        for (int k = 0; k < 128; k++) {
            const u32 bit = (ml[k * 16 + l15] != 0) ? 1u : 0u;
            if (k < 32)      mw0 |= bit << k;
            else if (k < 64) mw1 |= bit << (k - 32);
            else if (k < 96) mw2 |= bit << (k - 64);
            else             mw3 |= bit << (k - 96);
        }
    }
    __syncthreads();  // pack reads retired before Kbf[0] reuse

    auto STAGE = [&](int tt, int buf) {
#pragma unroll
        for (int s = 0; s < 2; s++) {
            gl_lds16(baseK[s] + (size_t)tt * 4096, &Kbf[buf][(wave * 8 + s * 4) * 128]);
            gl_lds16(baseV[s] + (size_t)tt * 4096, &Vbf[buf][(wave * 8 + s * 4) * 128]);
        }
    };

    float lsum[4] = {0.f, 0.f, 0.f, 0.f};
    f32x4 O[4];
#pragma unroll
    for (int dt = 0; dt < 4; dt++) O[dt] = (f32x4){0.f, 0.f, 0.f, 0.f};

    const float C1 = 1.44269504f / 64.0f;   // log2(e)/64
    const int NT = Sn / 64;  // 32
    STAGE(0, 0);
    STAGE(1, 1);

#pragma unroll 2
    for (int tt = 0; tt < NT; ++tt) {
        const int buf = tt & 1;
        if (tt < NT - 1) asm volatile("s_waitcnt vmcnt(4)" ::: "memory");
        else             asm volatile("s_waitcnt vmcnt(0)" ::: "memory");
        barrier_nodrain();

        // ---- S = Q K^T ----
        f32x4 s[4];
#pragma unroll
        for (int ct = 0; ct < 4; ct++) s[ct] = (f32x4){0.f, 0.f, 0.f, 0.f};
#pragma unroll
        for (int ct = 0; ct < 4; ct++)
#pragma unroll
            for (int ks = 0; ks < 2; ks++) {
                const bf16x8 bk = ldfrag(&Kbf[buf][(ct * 8 + ks * 4 + quad) * 128 + l15 * 8]);
                s[ct] = __builtin_amdgcn_mfma_f32_16x16x32_bf16(aq[ks], bk, s[ct], 0, 0, 0);
            }

        // ---- mask bias (exp2 domain): k = tt*4 + ct ----
        const int wsel = tt >> 3;
        const u32 cw = (wsel == 0) ? mw0 : (wsel == 1) ? mw1 : (wsel == 2) ? mw2 : mw3;
        const int sh = (tt & 7) * 4;
        float badd[4];
#pragma unroll
        for (int ct = 0; ct < 4; ct++)
            badd[ct] = (!use_mask || ((cw >> (sh + ct)) & 1u)) ? 0.0f : -1.44269504e9f;

        const int prowb = wave * 16 + quad * 4;
        const int rrow = wave * 16 + l15;

        // ---- softmax ct 0-1; P = exp2(s*C1 + badd) ----
#pragma unroll
        for (int ct = 0; ct < 2; ct++)
#pragma unroll
            for (int r = 0; r < 4; r++) {
                const float pp = __builtin_amdgcn_exp2f(fmaf(s[ct][r], C1, badd[ct]));
                lsum[r] += pp;
                Ps[(prowb + r) * 64 + ((ct * 16 + l15) ^ (((prowb + r) & 7) << 3))] = f2bf(pp);
            }
        asm volatile("s_waitcnt lgkmcnt(0)" ::: "memory");  // ct0-1 writes visible
        const bf16x8 pa0 = ldfrag(&Ps[rrow * 64 + ((quad * 8) ^ ((l15 & 7) << 3))]);

        // ---- softmax ct 2-3 (co-issues with PV kc=0 MFMAs below) ----
#pragma unroll
        for (int ct = 2; ct < 4; ct++)
#pragma unroll
            for (int r = 0; r < 4; r++) {
                const float pp = __builtin_amdgcn_exp2f(fmaf(s[ct][r], C1, badd[ct]));
                lsum[r] += pp;
                Ps[(prowb + r) * 64 + ((ct * 16 + l15) ^ (((prowb + r) & 7) << 3))] = f2bf(pp);
            }

        // ---- O += P V, kc = 0 ----
#pragma unroll
        for (int dt = 0; dt < 4; dt++) {
            const bf16x8 bvv = ldfrag(&Vbf[buf][(dt * 8 + quad) * 128 + l15 * 8]);
            O[dt] = __builtin_amdgcn_mfma_f32_16x16x32_bf16(pa0, bvv, O[dt], 0, 0, 0);
        }
        asm volatile("s_waitcnt lgkmcnt(0)" ::: "memory");  // ct2-3 writes visible
        const bf16x8 pa1 = ldfrag(&Ps[rrow * 64 + ((32 + quad * 8) ^ ((l15 & 7) << 3))]);

        // ---- O += P V, kc = 1 ----
#pragma unroll
        for (int dt = 0; dt < 4; dt++) {
            const bf16x8 bvv = ldfrag(&Vbf[buf][(dt * 8 + 4 + quad) * 128 + l15 * 8]);
            O[dt] = __builtin_amdgcn_mfma_f32_16x16x32_bf16(pa1, bvv, O[dt], 0, 0, 0);
        }

        asm volatile("s_waitcnt lgkmcnt(0)" ::: "memory");
        barrier_nodrain();
        if (tt + 2 < NT) STAGE(tt + 2, buf);
    }

    // ---- reduce l across the 16 column-lanes ----
#pragma unroll
    for (int r = 0; r < 4; r++) {
#pragma unroll
        for (int off = 1; off < 16; off <<= 1) lsum[r] += __shfl_xor(lsum[r], off);
    }
    float linv[4];
#pragma unroll
    for (int r = 0; r < 4; r++) linv[r] = 1.0f / fmaxf(lsum[r], 1e-30f);

    // ---- epilogue: restage O in Ps (plain), then store CHUNK-TILED ----
    __syncthreads();
#pragma unroll
    for (int r = 0; r < 4; r++)
#pragma unroll
        for (int dt = 0; dt < 4; dt++)
            Ps[(wave * 16 + quad * 4 + r) * 64 + dt * 16 + l15] = f2bf(O[dt][r] * linv[r]);
    __syncthreads();
    const size_t cbase = ((size_t)(b * Hn + h) * 32 + qt) * 4096;  // == Q slab (8KB)
#pragma unroll
    for (int e2 = 0; e2 < 2; e2++) {
        const int tid = t + 256 * e2;
        const int row = tid >> 3, cg = tid & 7;
        const int sub16 = row >> 4, dsub = cg >> 2, quadk = cg & 3;
        const uint4 v = *(const uint4*)&Ps[row * 64 + cg * 8];
        *(uint4*)(Aw + cbase + (size_t)(sub16 * 2 + dsub) * 512
                  + (quadk * 16 + (row & 15)) * 8) = v;
    }
}

// ---------------------------------------------------------------------------
extern "C" void kernel_launch(void* const* d_in, const int* in_sizes, int n_in,
                              void* d_out, int out_size, void* d_ws, size_t ws_size,
                              hipStream_t stream) {
    const float* query = (const float*)d_in[0];
    const float* key   = (const float*)d_in[1];
    const float* value = (const float*)d_in[2];
    const int*   pmask = (const int*)d_in[3];
    const int*   tstat = (const int*)d_in[4];
    const float* Wq  = (const float*)d_in[5];
    const float* bq  = (const float*)d_in[6];
    const float* Wk  = (const float*)d_in[7];
    const float* bk  = (const float*)d_in[8];
    const float* Wv  = (const float*)d_in[9];
    const float* bv  = (const float*)d_in[10];
    const float* Wf  = (const float*)d_in[11];
    const float* bfb = (const float*)d_in[12];
    float* outp = (float*)d_out;

    // ws (32 MB): Qw(8, attn-out alias) | Kw tiled(8) | VwT tiled(8) | Wt tiled 4x2MB(8)
    const size_t NT = (size_t)Bn * Sn * DIMn;
    u16* Qw  = (u16*)d_ws;
    u16* Kw  = Qw + NT;
    u16* VwT = Kw + NT;
    u16* Wt  = VwT + NT;
    const size_t WSZ = (size_t)DIMn * DIMn;

    prep_weights<<<dim3(16, 16, 4), 256, 0, stream>>>(Wq, Wk, Wv, Wf, Wt);

    gemm_qkv<<<768, 256, 0, stream>>>(query, key, value, Wt, bq, bk, bv, Qw, Kw, VwT);

    attn_mfma<<<1024, 256, 0, stream>>>(Qw, Kw, VwT, pmask, tstat, Qw);

    gemm_final<<<512, 256, 0, stream>>>(Qw, Wt + 3 * WSZ, bfb, outp);
}